// Round 1
// baseline (489.989 us; speedup 1.0000x reference)
//
#include <hip/hip_runtime.h>
#include <math.h>

// Sizes fixed by the problem.
#define BB 8
#define HH 256
#define WW 256
#define CC 64
// modes: kx in {0..31} u {224..255} (64 total), ky in {0..31}

__device__ inline void build_tw(float2* tw) {
    // tw[t] = (cos(2*pi*t/256), sin(2*pi*t/256))
    for (int t = threadIdx.x; t < 256; t += blockDim.x) {
        float ang = (float)t * (6.283185307179586f / 256.0f);
        float s, c;
        sincosf(ang, &s, &c);
        tw[t] = make_float2(c, s);
    }
}

// ---------------------------------------------------------------------------
// K1: V[b][x][ky*64+i] = sum_y u[b,x,y,i] * e^{-2pi i ky y/256}
// grid = B*H blocks (one (b,x) row), 256 threads.
// thread: ky = tid&31 fixed, i0 = (tid>>6)*16 + ((tid>>5)&1)*8, 8 i's.
// ---------------------------------------------------------------------------
__global__ __launch_bounds__(256) void k_fwd_y(const float* __restrict__ u,
                                               float2* __restrict__ V) {
    __shared__ float2 tw[256];
    __shared__ float2 vtile[32 * 65];
    build_tw(tw);
    __syncthreads();

    int b = blockIdx.x >> 8;
    int x = blockIdx.x & 255;
    int tid = threadIdx.x;
    int ky = tid & 31;
    int g = (tid >> 5) & 1;
    int w = tid >> 6;
    int i0 = w * 16 + g * 8;

    const float* up = u + ((size_t)(b * HH + x)) * (WW * CC) + i0;

    float ar0=0,ar1=0,ar2=0,ar3=0,ar4=0,ar5=0,ar6=0,ar7=0;
    float ai0=0,ai1=0,ai2=0,ai3=0,ai4=0,ai5=0,ai6=0,ai7=0;

    for (int y = 0; y < 256; ++y) {
        const float* row = up + (size_t)y * CC;
        float4 va = *(const float4*)(row);
        float4 vb = *(const float4*)(row + 4);
        float2 cs = tw[(ky * y) & 255];
        float c = cs.x, s = cs.y;
        ar0 += va.x * c; ai0 -= va.x * s;
        ar1 += va.y * c; ai1 -= va.y * s;
        ar2 += va.z * c; ai2 -= va.z * s;
        ar3 += va.w * c; ai3 -= va.w * s;
        ar4 += vb.x * c; ai4 -= vb.x * s;
        ar5 += vb.y * c; ai5 -= vb.y * s;
        ar6 += vb.z * c; ai6 -= vb.z * s;
        ar7 += vb.w * c; ai7 -= vb.w * s;
    }

    int base = ky * 65 + i0;
    vtile[base + 0] = make_float2(ar0, ai0);
    vtile[base + 1] = make_float2(ar1, ai1);
    vtile[base + 2] = make_float2(ar2, ai2);
    vtile[base + 3] = make_float2(ar3, ai3);
    vtile[base + 4] = make_float2(ar4, ai4);
    vtile[base + 5] = make_float2(ar5, ai5);
    vtile[base + 6] = make_float2(ar6, ai6);
    vtile[base + 7] = make_float2(ar7, ai7);
    __syncthreads();

    float2* vp = V + (size_t)(b * HH + x) * 2048;
    #pragma unroll
    for (int k = 0; k < 8; ++k) {
        int e = tid + 256 * k;
        vp[e] = vtile[(e >> 6) * 65 + (e & 63)];
    }
}

// ---------------------------------------------------------------------------
// K2: U[j][ky][b][i] = sum_x V[b][x][ky*64+i] * e^{-2pi i kxa(j) x /256}
// j=0..63 maps to kxa = j (j<32) or j+192 (j>=32).
// grid = B*32 blocks (b,ky), 1024 threads: i = tid&63, w = tid>>6 (0..15),
// thread owns j in {w, w+16, w+32, w+48}.
// ---------------------------------------------------------------------------
__global__ __launch_bounds__(1024) void k_fwd_x(const float2* __restrict__ V,
                                                float2* __restrict__ U) {
    __shared__ float2 tw[256];
    __shared__ float2 vbuf[4][64];
    build_tw(tw);

    int b = blockIdx.x >> 5;
    int ky = blockIdx.x & 31;
    int tid = threadIdx.x;
    int i = tid & 63;
    int w = tid >> 6; // 0..15

    float2 a0 = {0, 0}, a1 = {0, 0}, a2 = {0, 0}, a3 = {0, 0};
    const float2* vp = V + (size_t)b * HH * 2048 + ky * 64;

    __syncthreads();
    for (int x0 = 0; x0 < 256; x0 += 4) {
        if (tid < 256) {
            int xx = tid >> 6, ii = tid & 63;
            vbuf[xx][ii] = vp[(size_t)(x0 + xx) * 2048 + ii];
        }
        __syncthreads();
        #pragma unroll
        for (int xx = 0; xx < 4; ++xx) {
            int xa = x0 + xx;
            float2 v = vbuf[xx][i];
            float2 csd = tw[(16 * xa) & 255];
            // first half: kxa = w, w+16
            float2 cs = tw[(w * xa) & 255];
            float c = cs.x, s = cs.y;
            a0.x += v.x * c + v.y * s;  a0.y += v.y * c - v.x * s;
            { float cn = c * csd.x - s * csd.y, sn = s * csd.x + c * csd.y; c = cn; s = sn; }
            a1.x += v.x * c + v.y * s;  a1.y += v.y * c - v.x * s;
            // second half: kxa = w+224 (j=w+32), w+240 (j=w+48)
            cs = tw[((w + 224) * xa) & 255];
            c = cs.x; s = cs.y;
            a2.x += v.x * c + v.y * s;  a2.y += v.y * c - v.x * s;
            { float cn = c * csd.x - s * csd.y, sn = s * csd.x + c * csd.y; c = cn; s = sn; }
            a3.x += v.x * c + v.y * s;  a3.y += v.y * c - v.x * s;
        }
        __syncthreads();
    }

    U[((size_t)((w +  0) * 32 + ky) * 8 + b) * 64 + i] = a0;
    U[((size_t)((w + 16) * 32 + ky) * 8 + b) * 64 + i] = a1;
    U[((size_t)((w + 32) * 32 + ky) * 8 + b) * 64 + i] = a2;
    U[((size_t)((w + 48) * 32 + ky) * 8 + b) * 64 + i] = a3;
}

// ---------------------------------------------------------------------------
// K3: weight transpose: Wt[j][ky][i][o] = (w_r[i,o,kxl,ky], w_i[i,o,kxl,ky])
// j = sel*32 + kxl (sel 0 = pos, 1 = neg). grid = 64*32*2 blocks (i, kxl, sel).
// ---------------------------------------------------------------------------
__global__ __launch_bounds__(256) void k_wt(const float* __restrict__ wpr,
                                            const float* __restrict__ wpi,
                                            const float* __restrict__ wnr,
                                            const float* __restrict__ wni,
                                            float2* __restrict__ Wt) {
    __shared__ float2 tile[64 * 33];
    int i_ = blockIdx.x & 63;
    int kxl = (blockIdx.x >> 6) & 31;
    int sel = blockIdx.x >> 11;
    const float* sr = sel ? wnr : wpr;
    const float* si = sel ? wni : wpi;
    int tid = threadIdx.x;

    #pragma unroll
    for (int k = 0; k < 8; ++k) {
        int e = tid + 256 * k;
        int o = e >> 5, kyy = e & 31;
        size_t src = ((size_t)(i_ * 64 + o) * 32 + kxl) * 32 + kyy;
        tile[o * 33 + kyy] = make_float2(sr[src], si[src]);
    }
    __syncthreads();
    int j = sel * 32 + kxl;
    #pragma unroll
    for (int k = 0; k < 8; ++k) {
        int e = tid + 256 * k;
        int o = e & 63, kyy = e >> 6;
        Wt[((size_t)(j * 32 + kyy) * 64 + i_) * 64 + o] = tile[o * 33 + kyy];
    }
}

// ---------------------------------------------------------------------------
// K4: OF[b][ky][j][o] = sum_i U[j][ky][b][i] * Wt[j][ky][i][o]  (complex)
// grid = 64*32 blocks (j,ky), 256 threads: o = tid&63, b0 = tid>>6 -> b0, b0+4
// ---------------------------------------------------------------------------
__global__ __launch_bounds__(256) void k_mode(const float2* __restrict__ U,
                                              const float2* __restrict__ Wt,
                                              float2* __restrict__ OF) {
    __shared__ float2 uS[8 * 64];
    __shared__ float2 wS[64 * 64];
    int j = blockIdx.x >> 5;
    int ky = blockIdx.x & 31;
    int tid = threadIdx.x;

    const float2* up = U + (size_t)(j * 32 + ky) * 8 * 64;
    uS[tid] = up[tid];
    uS[tid + 256] = up[tid + 256];
    const float2* wp = Wt + (size_t)(j * 32 + ky) * 64 * 64;
    #pragma unroll
    for (int k = 0; k < 16; ++k) wS[tid + 256 * k] = wp[tid + 256 * k];
    __syncthreads();

    int o = tid & 63, b0 = tid >> 6;
    float2 a0 = {0, 0}, a1 = {0, 0};
    #pragma unroll 8
    for (int i = 0; i < 64; ++i) {
        float2 wv = wS[i * 64 + o];
        float2 u0 = uS[b0 * 64 + i];
        float2 u1 = uS[(b0 + 4) * 64 + i];
        a0.x += u0.x * wv.x - u0.y * wv.y;  a0.y += u0.x * wv.y + u0.y * wv.x;
        a1.x += u1.x * wv.x - u1.y * wv.y;  a1.y += u1.x * wv.y + u1.y * wv.x;
    }
    OF[((size_t)(b0 * 32 + ky) * 64 + j) * 64 + o] = a0;
    OF[((size_t)((b0 + 4) * 32 + ky) * 64 + j) * 64 + o] = a1;
}

// ---------------------------------------------------------------------------
// K5: A[b][x][ky][o] = scale * sum_j OF[b][ky][j][o] * e^{+2pi i kxa(j) x/256}
// scale = (ky==0 ? 1 : 2) / 65536  (irfft normalization + hermitian factor)
// grid = 512 blocks (b, ky, xhalf), 1024 threads: o = tid&63, w = tid>>6,
// x = xh*128 + w + 16r, r 0..7.
// ---------------------------------------------------------------------------
__global__ __launch_bounds__(1024) void k_inv_x(const float2* __restrict__ OF,
                                                float2* __restrict__ A) {
    __shared__ float2 tw[256];
    __shared__ float2 ofS[64 * 64];
    int b = blockIdx.x >> 6;
    int ky = (blockIdx.x >> 1) & 31;
    int xh = blockIdx.x & 1;
    build_tw(tw);
    int tid = threadIdx.x;

    const float2* ofp = OF + (size_t)(b * 32 + ky) * 64 * 64;
    #pragma unroll
    for (int k = 0; k < 4; ++k) ofS[tid + 1024 * k] = ofp[tid + 1024 * k];
    __syncthreads();

    int o = tid & 63;
    int w = tid >> 6; // 0..15
    int xbase = xh * 128 + w;

    float2 acc[8];
    #pragma unroll
    for (int r = 0; r < 8; ++r) acc[r] = make_float2(0.f, 0.f);

    for (int j = 0; j < 64; ++j) {
        float2 ofv = ofS[j * 64 + o];
        int kxa = (j < 32) ? j : (j + 192);
        float2 cs = tw[(kxa * xbase) & 255];
        float2 csd = tw[(kxa * 16) & 255];
        float c = cs.x, s = cs.y;
        #pragma unroll
        for (int r = 0; r < 8; ++r) {
            acc[r].x += ofv.x * c - ofv.y * s;
            acc[r].y += ofv.x * s + ofv.y * c;
            float cn = c * csd.x - s * csd.y;
            float sn = s * csd.x + c * csd.y;
            c = cn; s = sn;
        }
    }

    float scale = (ky == 0 ? 1.0f : 2.0f) * (1.0f / 65536.0f);
    #pragma unroll
    for (int r = 0; r < 8; ++r) {
        int x = xbase + 16 * r;
        A[((size_t)(b * 256 + x) * 32 + ky) * 64 + o] =
            make_float2(acc[r].x * scale, acc[r].y * scale);
    }
}

// ---------------------------------------------------------------------------
// K6: out[b,x,y,o] = sum_ky ( A.re*cos(2pi ky y/256) - A.im*sin(...) )
// y/y+128 parity split: even-ky sum Se, odd-ky sum So;
// out[y] = Se+So, out[y+128] = Se-So.
// grid = B*H blocks (b,x), 256 threads: o2 = tid&31 -> o2, o2+32; w = tid>>5,
// p (=y<128) in [w*16, w*16+16).
// ---------------------------------------------------------------------------
__global__ __launch_bounds__(256) void k_inv_y(const float2* __restrict__ A,
                                               float* __restrict__ out) {
    __shared__ float2 tw[256];
    build_tw(tw);

    int b = blockIdx.x >> 8;
    int x = blockIdx.x & 255;
    int tid = threadIdx.x;
    int o2 = tid & 31;
    int w = tid >> 5; // 0..7

    const float2* ap = A + (size_t)(b * 256 + x) * 32 * 64;
    float2 a_lo[32], a_hi[32];
    #pragma unroll
    for (int ky = 0; ky < 32; ++ky) {
        a_lo[ky] = ap[ky * 64 + o2];
        a_hi[ky] = ap[ky * 64 + o2 + 32];
    }
    __syncthreads();

    float* op = out + (size_t)(b * 256 + x) * (256 * 64);
    for (int p = w * 16; p < w * 16 + 16; ++p) {
        float se0 = 0.f, so0 = 0.f, se1 = 0.f, so1 = 0.f;
        #pragma unroll
        for (int ky = 0; ky < 32; ky += 2) {
            float2 cs0 = tw[(ky * p) & 255];
            se0 += a_lo[ky].x * cs0.x - a_lo[ky].y * cs0.y;
            se1 += a_hi[ky].x * cs0.x - a_hi[ky].y * cs0.y;
            float2 cs1 = tw[((ky + 1) * p) & 255];
            so0 += a_lo[ky + 1].x * cs1.x - a_lo[ky + 1].y * cs1.y;
            so1 += a_hi[ky + 1].x * cs1.x - a_hi[ky + 1].y * cs1.y;
        }
        op[p * 64 + o2]              = se0 + so0;
        op[p * 64 + o2 + 32]         = se1 + so1;
        op[(p + 128) * 64 + o2]      = se0 - so0;
        op[(p + 128) * 64 + o2 + 32] = se1 - so1;
    }
}

// ---------------------------------------------------------------------------
extern "C" void kernel_launch(void* const* d_in, const int* in_sizes, int n_in,
                              void* d_out, int out_size, void* d_ws, size_t ws_size,
                              hipStream_t stream) {
    const float* u   = (const float*)d_in[0];
    const float* wpr = (const float*)d_in[1];
    const float* wpi = (const float*)d_in[2];
    const float* wnr = (const float*)d_in[3];
    const float* wni = (const float*)d_in[4];
    float* out = (float*)d_out;

    char* ws = (char*)d_ws;
    // Wt: 64*32*64*64 float2 = 64 MiB
    // U : 64*32*8*64  float2 =  8 MiB
    // OF:  8*32*64*64 float2 =  8 MiB
    // V : 8*256*32*64 float2 = 32 MiB (A aliases V: V dead before A written)
    float2* Wt = (float2*)(ws);
    float2* U  = (float2*)(ws + 67108864);
    float2* OF = (float2*)(ws + 75497472);
    float2* V  = (float2*)(ws + 83886080);
    float2* A  = V;

    k_fwd_y<<<BB * HH, 256, 0, stream>>>(u, V);
    k_wt<<<64 * 32 * 2, 256, 0, stream>>>(wpr, wpi, wnr, wni, Wt);
    k_fwd_x<<<BB * 32, 1024, 0, stream>>>(V, U);
    k_mode<<<64 * 32, 256, 0, stream>>>(U, Wt, OF);
    k_inv_x<<<512, 1024, 0, stream>>>(OF, A);
    k_inv_y<<<BB * HH, 256, 0, stream>>>(A, out);
}

// Round 2
// 356.844 us; speedup vs baseline: 1.3731x; 1.3731x over previous
//
#include <hip/hip_runtime.h>
#include <math.h>

// Sizes fixed by the problem.
#define BB 8
#define HH 256
#define WW 256
#define CC 64
// modes: kx in {0..31} u {224..255} (64 total), ky in {0..31}

__device__ inline void build_tw(float2* tw) {
    // tw[t] = (cos(2*pi*t/256), sin(2*pi*t/256))
    for (int t = threadIdx.x; t < 256; t += blockDim.x) {
        float ang = (float)t * (6.283185307179586f / 256.0f);
        float s, c;
        sincosf(ang, &s, &c);
        tw[t] = make_float2(c, s);
    }
}

// ---------------------------------------------------------------------------
// K1: V[b][x][ky*64+i] = sum_y u[b,x,y,i] * e^{-2pi i ky y/256}
// Radix-2 in y: even ky use ue = u[y]+u[y+128], odd ky use uo = u[y]-u[y+128],
// y' in [0,128).
// grid = B*H blocks (one (b,x) row), 256 threads.
// thread: ky = tid&31, i0 = (tid>>5)*8 (8 channels).
// u row staged in LDS in 4 tiles of 32 y-pairs (coalesced global loads).
// Twiddles: per-ky table twk[ky][y] (pad 129 -> 2-way conflicts only = free).
// ---------------------------------------------------------------------------
__global__ __launch_bounds__(256) void k_fwd_y(const float* __restrict__ u,
                                               float2* __restrict__ V) {
    __shared__ float ue[32 * 68];      // +4 pad: keeps float4 alignment
    __shared__ float uo[32 * 68];
    __shared__ float2 twk[32 * 129];   // aliased as vtile[32*65] in epilogue

    int tid = threadIdx.x;

    // build per-ky twiddle table: twk[ky][y] = e^{-i 2pi (ky*y mod 256)/256} conj-parts
    #pragma unroll
    for (int k = 0; k < 16; ++k) {
        int e = tid + 256 * k;
        int kyy = e >> 7, y = e & 127;
        int t = (kyy * y) & 255;
        float ang = (float)t * (6.283185307179586f / 256.0f);
        float s, c;
        sincosf(ang, &s, &c);
        twk[kyy * 129 + y] = make_float2(c, s);
    }

    int b = blockIdx.x >> 8;
    int x = blockIdx.x & 255;
    int ky = tid & 31;
    int i0 = (tid >> 5) * 8;
    int yy = tid >> 3;
    int c0 = (tid & 7) * 8;

    const float* ub = u + ((size_t)(b * HH + x)) * (WW * CC);

    float ar[8], ai[8];
    #pragma unroll
    for (int c = 0; c < 8; ++c) { ar[c] = 0.f; ai[c] = 0.f; }

    const float* rbase = (ky & 1) ? uo : ue;
    const float2* tk = twk + ky * 129;

    for (int yt = 0; yt < 4; ++yt) {
        const float* plo = ub + (size_t)(yt * 32 + yy) * CC + c0;
        const float* phi = plo + 128 * CC;
        float4 l0 = *(const float4*)(plo);
        float4 l1 = *(const float4*)(plo + 4);
        float4 h0 = *(const float4*)(phi);
        float4 h1 = *(const float4*)(phi + 4);

        __syncthreads();   // prev tile's reads done (also twk build on yt==0)
        int wb = yy * 68 + c0;
        *(float4*)(ue + wb)     = make_float4(l0.x + h0.x, l0.y + h0.y, l0.z + h0.z, l0.w + h0.w);
        *(float4*)(ue + wb + 4) = make_float4(l1.x + h1.x, l1.y + h1.y, l1.z + h1.z, l1.w + h1.w);
        *(float4*)(uo + wb)     = make_float4(l0.x - h0.x, l0.y - h0.y, l0.z - h0.z, l0.w - h0.w);
        *(float4*)(uo + wb + 4) = make_float4(l1.x - h1.x, l1.y - h1.y, l1.z - h1.z, l1.w - h1.w);
        __syncthreads();

        #pragma unroll
        for (int y2 = 0; y2 < 32; ++y2) {
            int y = yt * 32 + y2;
            const float* s8 = rbase + y2 * 68 + i0;
            float2 cs = tk[y];
            #pragma unroll
            for (int c = 0; c < 8; ++c) {
                float v = s8[c];
                ar[c] += v * cs.x;
                ai[c] -= v * cs.y;
            }
        }
    }

    __syncthreads();               // twk dead from here; reuse as vtile
    float2* vtile = twk;
    #pragma unroll
    for (int c = 0; c < 8; ++c)
        vtile[ky * 65 + i0 + c] = make_float2(ar[c], ai[c]);
    __syncthreads();

    float2* vp = V + (size_t)(b * HH + x) * 2048;
    #pragma unroll
    for (int k = 0; k < 8; ++k) {
        int e = tid + 256 * k;
        vp[e] = vtile[(e >> 6) * 65 + (e & 63)];
    }
}

// ---------------------------------------------------------------------------
// K2: U[j][ky][b][i] = sum_x V[b][x][ky*64+i] * e^{-2pi i kxa(j) x /256}
// j=0..63 maps to kxa = j (j<32) or j+192 (j>=32).
// grid = B*32 blocks (b,ky), 1024 threads: i = tid&63, w = tid>>6 (0..15),
// thread owns j in {w, w+16, w+32, w+48}. 16 x-rows staged per barrier.
// ---------------------------------------------------------------------------
__global__ __launch_bounds__(1024) void k_fwd_x(const float2* __restrict__ V,
                                                float2* __restrict__ U) {
    __shared__ float2 tw[256];
    __shared__ float2 vbuf[16][64];
    build_tw(tw);

    int b = blockIdx.x >> 5;
    int ky = blockIdx.x & 31;
    int tid = threadIdx.x;
    int i = tid & 63;
    int w = tid >> 6; // 0..15

    float2 a0 = {0, 0}, a1 = {0, 0}, a2 = {0, 0}, a3 = {0, 0};
    const float2* vp = V + (size_t)b * HH * 2048 + ky * 64;

    __syncthreads();
    for (int x0 = 0; x0 < 256; x0 += 16) {
        vbuf[w][i] = vp[(size_t)(x0 + w) * 2048 + i];
        __syncthreads();
        #pragma unroll
        for (int xx = 0; xx < 16; ++xx) {
            int xa = x0 + xx;
            float2 v = vbuf[xx][i];
            float2 csd = tw[(16 * xa) & 255];
            // first half: kxa = w, w+16
            float2 cs = tw[(w * xa) & 255];
            float c = cs.x, s = cs.y;
            a0.x += v.x * c + v.y * s;  a0.y += v.y * c - v.x * s;
            { float cn = c * csd.x - s * csd.y, sn = s * csd.x + c * csd.y; c = cn; s = sn; }
            a1.x += v.x * c + v.y * s;  a1.y += v.y * c - v.x * s;
            // second half: kxa = w+224 (j=w+32), w+240 (j=w+48)
            cs = tw[((w + 224) * xa) & 255];
            c = cs.x; s = cs.y;
            a2.x += v.x * c + v.y * s;  a2.y += v.y * c - v.x * s;
            { float cn = c * csd.x - s * csd.y, sn = s * csd.x + c * csd.y; c = cn; s = sn; }
            a3.x += v.x * c + v.y * s;  a3.y += v.y * c - v.x * s;
        }
        __syncthreads();
    }

    U[((size_t)((w +  0) * 32 + ky) * 8 + b) * 64 + i] = a0;
    U[((size_t)((w + 16) * 32 + ky) * 8 + b) * 64 + i] = a1;
    U[((size_t)((w + 32) * 32 + ky) * 8 + b) * 64 + i] = a2;
    U[((size_t)((w + 48) * 32 + ky) * 8 + b) * 64 + i] = a3;
}

// ---------------------------------------------------------------------------
// K3 (fused k_wt + k_mode):
// OF[b][ky][j][o] = sum_i U[j][ky][b][i] * (wr[i,o,kxl,ky], wi[i,o,kxl,ky])
// Reads raw weights directly (no transpose kernel): per (i,o) pair the
// ky0..ky0+7 run is 32 B contiguous; blocks (j,kyt) and (j,kyt+1) are 64
// blockIdx apart -> same XCD (round-robin %8) -> share the 64 B line in L2.
// grid = 512 blocks: bx = j + 64*kyt + 256*oh (j 0..63, kyt 0..3, oh 0..1).
// 256 threads. Block computes OF[all b][ky0..ky0+7][j][oh*32..+31].
// ---------------------------------------------------------------------------
__global__ __launch_bounds__(256) void k_modew(const float* __restrict__ wpr,
                                               const float* __restrict__ wpi,
                                               const float* __restrict__ wnr,
                                               const float* __restrict__ wni,
                                               const float2* __restrict__ U,
                                               float2* __restrict__ OF) {
    __shared__ float2 uS[8 * 8 * 64];   // [kyr][b][i]   32 KB
    __shared__ float2 wS[8 * 8 * 32];   // [kyr][ir][o32] 16 KB (per i-tile)

    int bx = blockIdx.x;
    int j   = bx & 63;
    int kyt = (bx >> 6) & 3;
    int oh  = bx >> 8;
    int ky0 = kyt * 8;
    int sel = j >> 5, kxl = j & 31;
    const float* sr = sel ? wnr : wpr;
    const float* si = sel ? wni : wpi;
    int tid = threadIdx.x;

    // stage U slice: contiguous 4096 float2
    const float2* up = U + (size_t)(j * 32 + ky0) * 512;
    #pragma unroll
    for (int k = 0; k < 16; ++k) uS[tid + 256 * k] = up[tid + 256 * k];

    int o32 = tid & 31;
    int bh  = tid >> 5;            // 0..7 = batch
    int irS = tid >> 5;            // staging: ir = tid>>5, oo = tid&31
    int ooS = tid & 31;

    float2 acc[8];
    #pragma unroll
    for (int k = 0; k < 8; ++k) acc[k] = make_float2(0.f, 0.f);

    for (int it = 0; it < 8; ++it) {
        __syncthreads();  // uS ready (it==0) / wS reads of prev tile done
        {
            int ig = it * 8 + irS;
            int og = oh * 32 + ooS;
            size_t base = (((size_t)(ig * 64 + og)) * 32 + kxl) * 32 + ky0;
            float4 r0 = *(const float4*)(sr + base);
            float4 r1 = *(const float4*)(sr + base + 4);
            float4 q0 = *(const float4*)(si + base);
            float4 q1 = *(const float4*)(si + base + 4);
            float2* wrow = wS + irS * 32 + ooS;
            wrow[0 * 256] = make_float2(r0.x, q0.x);
            wrow[1 * 256] = make_float2(r0.y, q0.y);
            wrow[2 * 256] = make_float2(r0.z, q0.z);
            wrow[3 * 256] = make_float2(r0.w, q0.w);
            wrow[4 * 256] = make_float2(r1.x, q1.x);
            wrow[5 * 256] = make_float2(r1.y, q1.y);
            wrow[6 * 256] = make_float2(r1.z, q1.z);
            wrow[7 * 256] = make_float2(r1.w, q1.w);
        }
        __syncthreads();
        #pragma unroll
        for (int ir = 0; ir < 8; ++ir) {
            int ig = it * 8 + ir;
            #pragma unroll
            for (int ky = 0; ky < 8; ++ky) {
                float2 wv = wS[ky * 256 + ir * 32 + o32];
                float2 uv = uS[ky * 512 + bh * 64 + ig];
                acc[ky].x += uv.x * wv.x - uv.y * wv.y;
                acc[ky].y += uv.x * wv.y + uv.y * wv.x;
            }
        }
    }

    int og = oh * 32 + o32;
    #pragma unroll
    for (int ky = 0; ky < 8; ++ky) {
        OF[((size_t)(bh * 32 + ky0 + ky) * 64 + j) * 64 + og] = acc[ky];
    }
}

// ---------------------------------------------------------------------------
// K4: A[b][x][ky][o] = scale * sum_j OF[b][ky][j][o] * e^{+2pi i kxa(j) x/256}
// scale = (ky==0 ? 1 : 2) / 65536. Loop-swapped: direct (broadcast) twiddle
// lookups instead of an 8-deep serial complex-multiply chain.
// grid = 512 blocks (b, ky, xhalf), 1024 threads: o = tid&63, w = tid>>6,
// x = xh*128 + w + 16r, r 0..7.
// ---------------------------------------------------------------------------
__global__ __launch_bounds__(1024) void k_inv_x(const float2* __restrict__ OF,
                                                float2* __restrict__ A) {
    __shared__ float2 tw[256];
    __shared__ float2 ofS[64 * 64];
    int b = blockIdx.x >> 6;
    int ky = (blockIdx.x >> 1) & 31;
    int xh = blockIdx.x & 1;
    build_tw(tw);
    int tid = threadIdx.x;

    const float2* ofp = OF + (size_t)(b * 32 + ky) * 4096;
    #pragma unroll
    for (int k = 0; k < 4; ++k) ofS[tid + 1024 * k] = ofp[tid + 1024 * k];
    __syncthreads();

    int o = tid & 63;
    int w = tid >> 6; // 0..15
    int xbase = xh * 128 + w;

    float2 acc[8];
    #pragma unroll
    for (int r = 0; r < 8; ++r) acc[r] = make_float2(0.f, 0.f);

    for (int j = 0; j < 64; ++j) {
        float2 ofv = ofS[j * 64 + o];
        int kxa = j + ((j >> 5) * 192);
        int idx  = (kxa * xbase) & 255;
        int step = (kxa * 16) & 255;
        #pragma unroll
        for (int r = 0; r < 8; ++r) {
            float2 cs = tw[idx];
            acc[r].x += ofv.x * cs.x - ofv.y * cs.y;
            acc[r].y += ofv.x * cs.y + ofv.y * cs.x;
            idx = (idx + step) & 255;
        }
    }

    float scale = (ky == 0 ? 1.0f : 2.0f) * (1.0f / 65536.0f);
    #pragma unroll
    for (int r = 0; r < 8; ++r) {
        int x = xbase + 16 * r;
        A[((size_t)(b * 256 + x) * 32 + ky) * 64 + o] =
            make_float2(acc[r].x * scale, acc[r].y * scale);
    }
}

// ---------------------------------------------------------------------------
// K5: out[b,x,y,o] = sum_ky ( A.re*cos(2pi ky y/256) - A.im*sin(...) )
// y/y+128 parity split: even-ky sum Se, odd-ky sum So;
// out[y] = Se+So, out[y+128] = Se-So.
// grid = B*H blocks (b,x), 256 threads: o2 = tid&31 -> o2, o2+32; w = tid>>5,
// p (=y<128) in [w*16, w*16+16).
// ---------------------------------------------------------------------------
__global__ __launch_bounds__(256) void k_inv_y(const float2* __restrict__ A,
                                               float* __restrict__ out) {
    __shared__ float2 tw[256];
    build_tw(tw);

    int b = blockIdx.x >> 8;
    int x = blockIdx.x & 255;
    int tid = threadIdx.x;
    int o2 = tid & 31;
    int w = tid >> 5; // 0..7

    const float2* ap = A + (size_t)(b * 256 + x) * 32 * 64;
    float2 a_lo[32], a_hi[32];
    #pragma unroll
    for (int ky = 0; ky < 32; ++ky) {
        a_lo[ky] = ap[ky * 64 + o2];
        a_hi[ky] = ap[ky * 64 + o2 + 32];
    }
    __syncthreads();

    float* op = out + (size_t)(b * 256 + x) * (256 * 64);
    for (int p = w * 16; p < w * 16 + 16; ++p) {
        float se0 = 0.f, so0 = 0.f, se1 = 0.f, so1 = 0.f;
        #pragma unroll
        for (int ky = 0; ky < 32; ky += 2) {
            float2 cs0 = tw[(ky * p) & 255];
            se0 += a_lo[ky].x * cs0.x - a_lo[ky].y * cs0.y;
            se1 += a_hi[ky].x * cs0.x - a_hi[ky].y * cs0.y;
            float2 cs1 = tw[((ky + 1) * p) & 255];
            so0 += a_lo[ky + 1].x * cs1.x - a_lo[ky + 1].y * cs1.y;
            so1 += a_hi[ky + 1].x * cs1.x - a_hi[ky + 1].y * cs1.y;
        }
        op[p * 64 + o2]              = se0 + so0;
        op[p * 64 + o2 + 32]         = se1 + so1;
        op[(p + 128) * 64 + o2]      = se0 - so0;
        op[(p + 128) * 64 + o2 + 32] = se1 - so1;
    }
}

// ---------------------------------------------------------------------------
extern "C" void kernel_launch(void* const* d_in, const int* in_sizes, int n_in,
                              void* d_out, int out_size, void* d_ws, size_t ws_size,
                              hipStream_t stream) {
    const float* u   = (const float*)d_in[0];
    const float* wpr = (const float*)d_in[1];
    const float* wpi = (const float*)d_in[2];
    const float* wnr = (const float*)d_in[3];
    const float* wni = (const float*)d_in[4];
    float* out = (float*)d_out;

    char* ws = (char*)d_ws;
    // U : 64*32*8*64  float2 =  8 MiB  @ 0
    // OF:  8*32*64*64 float2 =  8 MiB  @ 8 MiB
    // V : 8*256*32*64 float2 = 32 MiB  @ 16 MiB (A aliases V: V dead before A)
    float2* U  = (float2*)(ws);
    float2* OF = (float2*)(ws + 8388608);
    float2* V  = (float2*)(ws + 16777216);
    float2* A  = V;

    k_fwd_y<<<BB * HH, 256, 0, stream>>>(u, V);
    k_fwd_x<<<BB * 32, 1024, 0, stream>>>(V, U);
    k_modew<<<512, 256, 0, stream>>>(wpr, wpi, wnr, wni, U, OF);
    k_inv_x<<<512, 1024, 0, stream>>>(OF, A);
    k_inv_y<<<BB * HH, 256, 0, stream>>>(A, out);
}

// Round 3
// 297.856 us; speedup vs baseline: 1.6451x; 1.1980x over previous
//
#include <hip/hip_runtime.h>
#include <math.h>

// Sizes fixed by the problem.
#define BB 8
#define HH 256
#define WW 256
#define CC 64
// modes: kx in {0..31} u {224..255} (64 total), ky in {0..31}

__device__ inline void build_tw(float2* tw) {
    // tw[t] = (cos(2*pi*t/256), sin(2*pi*t/256))
    for (int t = threadIdx.x; t < 256; t += blockDim.x) {
        float ang = (float)t * (6.283185307179586f / 256.0f);
        float s, c;
        sincosf(ang, &s, &c);
        tw[t] = make_float2(c, s);
    }
}

__device__ inline void cmac(float2& a, float tx, float ty, float2 v) {
    a.x += tx * v.x - ty * v.y;
    a.y += tx * v.y + ty * v.x;
}

// ---------------------------------------------------------------------------
// K0: twiddle tables.
// Tf[x][j] = e^{-2pi i kxa(j) x/256}            (forward x-DFT operand)
// Ti[j][x] = (2/65536) e^{+2pi i kxa(j) x/256}  (inverse x-DFT operand,
//            hermitian factor 2 + irfft norm folded in; ky==0 fixes up 0.5x)
// kxa(j) = j (j<32) else j+192.
// ---------------------------------------------------------------------------
__global__ __launch_bounds__(256) void k_tw(float2* __restrict__ Tf,
                                            float2* __restrict__ Ti) {
    int e = blockIdx.x * 256 + threadIdx.x;   // 0..16383
    int x = e >> 6;
    int j = e & 63;
    int kxa = j + ((j >> 5) * 192);
    int tt = (kxa * x) & 255;
    float ang = (float)tt * (6.283185307179586f / 256.0f);
    float s, c;
    sincosf(ang, &s, &c);
    Tf[(size_t)x * 64 + j] = make_float2(c, -s);
    const float k = 2.0f / 65536.0f;
    Ti[(size_t)j * 256 + x] = make_float2(c * k, s * k);
}

// ---------------------------------------------------------------------------
// K1: V[b][x][ky*64+i] = sum_y u[b,x,y,i] * e^{-2pi i ky y/256}
// Radix-2 in y (even/odd ky on u[y]±u[y+128]), u row staged in LDS,
// per-ky padded twiddle table. grid = B*H, 256 threads.
// ---------------------------------------------------------------------------
__global__ __launch_bounds__(256) void k_fwd_y(const float* __restrict__ u,
                                               float2* __restrict__ V) {
    __shared__ float ue[32 * 68];
    __shared__ float uo[32 * 68];
    __shared__ float2 twk[32 * 129];   // aliased as vtile[32*65] in epilogue

    int tid = threadIdx.x;

    #pragma unroll
    for (int k = 0; k < 16; ++k) {
        int e = tid + 256 * k;
        int kyy = e >> 7, y = e & 127;
        int t = (kyy * y) & 255;
        float ang = (float)t * (6.283185307179586f / 256.0f);
        float s, c;
        sincosf(ang, &s, &c);
        twk[kyy * 129 + y] = make_float2(c, s);
    }

    int b = blockIdx.x >> 8;
    int x = blockIdx.x & 255;
    int ky = tid & 31;
    int i0 = (tid >> 5) * 8;
    int yy = tid >> 3;
    int c0 = (tid & 7) * 8;

    const float* ub = u + ((size_t)(b * HH + x)) * (WW * CC);

    float ar[8], ai[8];
    #pragma unroll
    for (int c = 0; c < 8; ++c) { ar[c] = 0.f; ai[c] = 0.f; }

    const float* rbase = (ky & 1) ? uo : ue;
    const float2* tk = twk + ky * 129;

    for (int yt = 0; yt < 4; ++yt) {
        const float* plo = ub + (size_t)(yt * 32 + yy) * CC + c0;
        const float* phi = plo + 128 * CC;
        float4 l0 = *(const float4*)(plo);
        float4 l1 = *(const float4*)(plo + 4);
        float4 h0 = *(const float4*)(phi);
        float4 h1 = *(const float4*)(phi + 4);

        __syncthreads();
        int wb = yy * 68 + c0;
        *(float4*)(ue + wb)     = make_float4(l0.x + h0.x, l0.y + h0.y, l0.z + h0.z, l0.w + h0.w);
        *(float4*)(ue + wb + 4) = make_float4(l1.x + h1.x, l1.y + h1.y, l1.z + h1.z, l1.w + h1.w);
        *(float4*)(uo + wb)     = make_float4(l0.x - h0.x, l0.y - h0.y, l0.z - h0.z, l0.w - h0.w);
        *(float4*)(uo + wb + 4) = make_float4(l1.x - h1.x, l1.y - h1.y, l1.z - h1.z, l1.w - h1.w);
        __syncthreads();

        #pragma unroll
        for (int y2 = 0; y2 < 32; ++y2) {
            int y = yt * 32 + y2;
            const float* s8 = rbase + y2 * 68 + i0;
            float2 cs = tk[y];
            #pragma unroll
            for (int c = 0; c < 8; ++c) {
                float v = s8[c];
                ar[c] += v * cs.x;
                ai[c] -= v * cs.y;
            }
        }
    }

    __syncthreads();
    float2* vtile = twk;
    #pragma unroll
    for (int c = 0; c < 8; ++c)
        vtile[ky * 65 + i0 + c] = make_float2(ar[c], ai[c]);
    __syncthreads();

    float2* vp = V + (size_t)(b * HH + x) * 2048;
    #pragma unroll
    for (int k = 0; k < 8; ++k) {
        int e = tid + 256 * k;
        vp[e] = vtile[(e >> 6) * 65 + (e & 63)];
    }
}

// ---------------------------------------------------------------------------
// K2 (GEMM form): U[j][ky][b][i] = sum_x Tf[x][j] * V[b][x][ky*64+i]
// grid = 512: bx = jh + 2*ky + 64*b. 256 threads.
// thread: jr = t>>4, ir = t&15; owns j = jh*32+jr*2+{0,1}, i = ir+16*{0..3}.
// K tiled by 32 x-rows staged in LDS; operand reads conflict-free
// (T: 4-address broadcast; V: 8 B-stride across 16 lanes).
// ---------------------------------------------------------------------------
__global__ __launch_bounds__(256) void k_fwd_x(const float2* __restrict__ Tf,
                                               const float2* __restrict__ V,
                                               float2* __restrict__ U) {
    __shared__ float2 Ts[32 * 32];  // [xx][jj]  8 KB
    __shared__ float2 Vs[32 * 64];  // [xx][i]  16 KB

    int bx = blockIdx.x;
    int jh = bx & 1;
    int ky = (bx >> 1) & 31;
    int b  = bx >> 6;
    int t = threadIdx.x;
    int ir = t & 15;
    int jr = t >> 4;

    float2 acc[2][4];
    #pragma unroll
    for (int p = 0; p < 2; ++p)
        #pragma unroll
        for (int q = 0; q < 4; ++q) acc[p][q] = make_float2(0.f, 0.f);

    const float2* vb = V + (size_t)b * (HH * 2048) + ky * 64;
    int trow = t >> 3, tc8 = t & 7;

    for (int x0 = 0; x0 < 256; x0 += 32) {
        const float2* tsrc = Tf + (size_t)(x0 + trow) * 64 + jh * 32 + tc8 * 4;
        float4 tr0 = *(const float4*)(tsrc);
        float4 tr1 = *(const float4*)(tsrc + 2);
        const float2* vsrc = vb + (size_t)(x0 + trow) * 2048 + tc8 * 8;
        float4 vr0 = *(const float4*)(vsrc);
        float4 vr1 = *(const float4*)(vsrc + 2);
        float4 vr2 = *(const float4*)(vsrc + 4);
        float4 vr3 = *(const float4*)(vsrc + 6);

        __syncthreads();   // previous tile's LDS reads complete
        float2* td = &Ts[trow * 32 + tc8 * 4];
        *(float4*)(td)     = tr0;
        *(float4*)(td + 2) = tr1;
        float2* vd = &Vs[trow * 64 + tc8 * 8];
        *(float4*)(vd)     = vr0;
        *(float4*)(vd + 2) = vr1;
        *(float4*)(vd + 4) = vr2;
        *(float4*)(vd + 6) = vr3;
        __syncthreads();

        #pragma unroll
        for (int xx = 0; xx < 32; ++xx) {
            float4 tp = *(const float4*)&Ts[xx * 32 + jr * 2];
            float2 v0 = Vs[xx * 64 + ir];
            float2 v1 = Vs[xx * 64 + ir + 16];
            float2 v2 = Vs[xx * 64 + ir + 32];
            float2 v3 = Vs[xx * 64 + ir + 48];
            cmac(acc[0][0], tp.x, tp.y, v0);
            cmac(acc[0][1], tp.x, tp.y, v1);
            cmac(acc[0][2], tp.x, tp.y, v2);
            cmac(acc[0][3], tp.x, tp.y, v3);
            cmac(acc[1][0], tp.z, tp.w, v0);
            cmac(acc[1][1], tp.z, tp.w, v1);
            cmac(acc[1][2], tp.z, tp.w, v2);
            cmac(acc[1][3], tp.z, tp.w, v3);
        }
    }

    int jbase = jh * 32 + jr * 2;
    #pragma unroll
    for (int p = 0; p < 2; ++p) {
        float2* up = U + ((size_t)((jbase + p) * 32 + ky) * 8 + b) * 64 + ir;
        #pragma unroll
        for (int q = 0; q < 4; ++q) up[16 * q] = acc[p][q];
    }
}

// ---------------------------------------------------------------------------
// K3 (fused weight-transpose + mode mul):
// OF[b][ky][j][o] = sum_i U[j][ky][b][i] * (wr[i,o,kxl,ky], wi[i,o,kxl,ky])
// grid = 512: bx = j + 64*kyt + 256*oh. 256 threads.
// ---------------------------------------------------------------------------
__global__ __launch_bounds__(256) void k_modew(const float* __restrict__ wpr,
                                               const float* __restrict__ wpi,
                                               const float* __restrict__ wnr,
                                               const float* __restrict__ wni,
                                               const float2* __restrict__ U,
                                               float2* __restrict__ OF) {
    __shared__ float2 uS[8 * 8 * 64];   // [kyr][b][i]   32 KB
    __shared__ float2 wS[8 * 8 * 32];   // [kyr][ir][o32] 16 KB (per i-tile)

    int bx = blockIdx.x;
    int j   = bx & 63;
    int kyt = (bx >> 6) & 3;
    int oh  = bx >> 8;
    int ky0 = kyt * 8;
    int sel = j >> 5, kxl = j & 31;
    const float* sr = sel ? wnr : wpr;
    const float* si = sel ? wni : wpi;
    int tid = threadIdx.x;

    const float2* up = U + (size_t)(j * 32 + ky0) * 512;
    #pragma unroll
    for (int k = 0; k < 16; ++k) uS[tid + 256 * k] = up[tid + 256 * k];

    int o32 = tid & 31;
    int bh  = tid >> 5;
    int irS = tid >> 5;
    int ooS = tid & 31;

    float2 acc[8];
    #pragma unroll
    for (int k = 0; k < 8; ++k) acc[k] = make_float2(0.f, 0.f);

    for (int it = 0; it < 8; ++it) {
        __syncthreads();
        {
            int ig = it * 8 + irS;
            int og = oh * 32 + ooS;
            size_t base = (((size_t)(ig * 64 + og)) * 32 + kxl) * 32 + ky0;
            float4 r0 = *(const float4*)(sr + base);
            float4 r1 = *(const float4*)(sr + base + 4);
            float4 q0 = *(const float4*)(si + base);
            float4 q1 = *(const float4*)(si + base + 4);
            float2* wrow = wS + irS * 32 + ooS;
            wrow[0 * 256] = make_float2(r0.x, q0.x);
            wrow[1 * 256] = make_float2(r0.y, q0.y);
            wrow[2 * 256] = make_float2(r0.z, q0.z);
            wrow[3 * 256] = make_float2(r0.w, q0.w);
            wrow[4 * 256] = make_float2(r1.x, q1.x);
            wrow[5 * 256] = make_float2(r1.y, q1.y);
            wrow[6 * 256] = make_float2(r1.z, q1.z);
            wrow[7 * 256] = make_float2(r1.w, q1.w);
        }
        __syncthreads();
        #pragma unroll
        for (int ir = 0; ir < 8; ++ir) {
            int ig = it * 8 + ir;
            #pragma unroll
            for (int ky = 0; ky < 8; ++ky) {
                float2 wv = wS[ky * 256 + ir * 32 + o32];
                float2 uv = uS[ky * 512 + bh * 64 + ig];
                acc[ky].x += uv.x * wv.x - uv.y * wv.y;
                acc[ky].y += uv.x * wv.y + uv.y * wv.x;
            }
        }
    }

    int og = oh * 32 + o32;
    #pragma unroll
    for (int ky = 0; ky < 8; ++ky) {
        OF[((size_t)(bh * 32 + ky0 + ky) * 64 + j) * 64 + og] = acc[ky];
    }
}

// ---------------------------------------------------------------------------
// K4 (GEMM form): A[b][x][ky][o] = sum_j Ti[j][x] * OF[b][ky][j][o]
// (hermitian 2x + 1/65536 folded into Ti; ky==0 corrected by 0.5 at write)
// grid = 1024: bx = xt + 4*ky + 128*b. 256 threads.
// thread: xr = t>>4, or = t&15; owns x = xt*64+xr*4+{0..3}, o = or+16*{0..3}.
// K=64 staged in two 32-j halves (32 KB LDS total).
// ---------------------------------------------------------------------------
__global__ __launch_bounds__(256) void k_inv_x(const float2* __restrict__ Ti,
                                               const float2* __restrict__ OF,
                                               float2* __restrict__ A) {
    __shared__ float2 Ts[32 * 64];   // [jj][x]  16 KB
    __shared__ float2 Os[32 * 64];   // [jj][o]  16 KB

    int bx = blockIdx.x;
    int xt = bx & 3;
    int ky = (bx >> 2) & 31;
    int b  = bx >> 7;
    int t = threadIdx.x;
    int or_ = t & 15;
    int xr = t >> 4;
    int xbase = xt * 64;

    float2 acc[4][4];
    #pragma unroll
    for (int p = 0; p < 4; ++p)
        #pragma unroll
        for (int q = 0; q < 4; ++q) acc[p][q] = make_float2(0.f, 0.f);

    int trow = t >> 3, tc8 = t & 7;
    const float2* ofb = OF + (size_t)(b * 32 + ky) * 4096;

    for (int kh = 0; kh < 2; ++kh) {
        const float2* tsrc = Ti + (size_t)(kh * 32 + trow) * 256 + xbase + tc8 * 8;
        float4 ta = *(const float4*)(tsrc);
        float4 tb = *(const float4*)(tsrc + 2);
        float4 tc = *(const float4*)(tsrc + 4);
        float4 td = *(const float4*)(tsrc + 6);
        const float2* osrc = ofb + (size_t)(kh * 32 + trow) * 64 + tc8 * 8;
        float4 oa = *(const float4*)(osrc);
        float4 ob = *(const float4*)(osrc + 2);
        float4 oc = *(const float4*)(osrc + 4);
        float4 od = *(const float4*)(osrc + 6);

        __syncthreads();
        float2* tdst = &Ts[trow * 64 + tc8 * 8];
        *(float4*)(tdst)     = ta;
        *(float4*)(tdst + 2) = tb;
        *(float4*)(tdst + 4) = tc;
        *(float4*)(tdst + 6) = td;
        float2* odst = &Os[trow * 64 + tc8 * 8];
        *(float4*)(odst)     = oa;
        *(float4*)(odst + 2) = ob;
        *(float4*)(odst + 4) = oc;
        *(float4*)(odst + 6) = od;
        __syncthreads();

        #pragma unroll
        for (int jj = 0; jj < 32; ++jj) {
            float4 tA = *(const float4*)&Ts[jj * 64 + xr * 4];
            float4 tB = *(const float4*)&Ts[jj * 64 + xr * 4 + 2];
            float2 o0 = Os[jj * 64 + or_];
            float2 o1 = Os[jj * 64 + or_ + 16];
            float2 o2 = Os[jj * 64 + or_ + 32];
            float2 o3 = Os[jj * 64 + or_ + 48];
            cmac(acc[0][0], tA.x, tA.y, o0);
            cmac(acc[0][1], tA.x, tA.y, o1);
            cmac(acc[0][2], tA.x, tA.y, o2);
            cmac(acc[0][3], tA.x, tA.y, o3);
            cmac(acc[1][0], tA.z, tA.w, o0);
            cmac(acc[1][1], tA.z, tA.w, o1);
            cmac(acc[1][2], tA.z, tA.w, o2);
            cmac(acc[1][3], tA.z, tA.w, o3);
            cmac(acc[2][0], tB.x, tB.y, o0);
            cmac(acc[2][1], tB.x, tB.y, o1);
            cmac(acc[2][2], tB.x, tB.y, o2);
            cmac(acc[2][3], tB.x, tB.y, o3);
            cmac(acc[3][0], tB.z, tB.w, o0);
            cmac(acc[3][1], tB.z, tB.w, o1);
            cmac(acc[3][2], tB.z, tB.w, o2);
            cmac(acc[3][3], tB.z, tB.w, o3);
        }
    }

    float sc = (ky == 0) ? 0.5f : 1.0f;
    #pragma unroll
    for (int p = 0; p < 4; ++p) {
        int x = xbase + xr * 4 + p;
        float2* ap = A + ((size_t)(b * 256 + x) * 32 + ky) * 64 + or_;
        #pragma unroll
        for (int q = 0; q < 4; ++q)
            ap[16 * q] = make_float2(acc[p][q].x * sc, acc[p][q].y * sc);
    }
}

// ---------------------------------------------------------------------------
// K5: out[b,x,y,o] = sum_ky ( A.re*cos(2pi ky y/256) - A.im*sin(...) )
// y/y+128 parity split. grid = B*H, 256 threads.
// ---------------------------------------------------------------------------
__global__ __launch_bounds__(256) void k_inv_y(const float2* __restrict__ A,
                                               float* __restrict__ out) {
    __shared__ float2 tw[256];
    build_tw(tw);

    int b = blockIdx.x >> 8;
    int x = blockIdx.x & 255;
    int tid = threadIdx.x;
    int o2 = tid & 31;
    int w = tid >> 5; // 0..7

    const float2* ap = A + (size_t)(b * 256 + x) * 32 * 64;
    float2 a_lo[32], a_hi[32];
    #pragma unroll
    for (int ky = 0; ky < 32; ++ky) {
        a_lo[ky] = ap[ky * 64 + o2];
        a_hi[ky] = ap[ky * 64 + o2 + 32];
    }
    __syncthreads();

    float* op = out + (size_t)(b * 256 + x) * (256 * 64);
    for (int p = w * 16; p < w * 16 + 16; ++p) {
        float se0 = 0.f, so0 = 0.f, se1 = 0.f, so1 = 0.f;
        #pragma unroll
        for (int ky = 0; ky < 32; ky += 2) {
            float2 cs0 = tw[(ky * p) & 255];
            se0 += a_lo[ky].x * cs0.x - a_lo[ky].y * cs0.y;
            se1 += a_hi[ky].x * cs0.x - a_hi[ky].y * cs0.y;
            float2 cs1 = tw[((ky + 1) * p) & 255];
            so0 += a_lo[ky + 1].x * cs1.x - a_lo[ky + 1].y * cs1.y;
            so1 += a_hi[ky + 1].x * cs1.x - a_hi[ky + 1].y * cs1.y;
        }
        op[p * 64 + o2]              = se0 + so0;
        op[p * 64 + o2 + 32]         = se1 + so1;
        op[(p + 128) * 64 + o2]      = se0 - so0;
        op[(p + 128) * 64 + o2 + 32] = se1 - so1;
    }
}

// ---------------------------------------------------------------------------
extern "C" void kernel_launch(void* const* d_in, const int* in_sizes, int n_in,
                              void* d_out, int out_size, void* d_ws, size_t ws_size,
                              hipStream_t stream) {
    const float* u   = (const float*)d_in[0];
    const float* wpr = (const float*)d_in[1];
    const float* wpi = (const float*)d_in[2];
    const float* wnr = (const float*)d_in[3];
    const float* wni = (const float*)d_in[4];
    float* out = (float*)d_out;

    char* ws = (char*)d_ws;
    // U : 64*32*8*64  float2 =  8 MiB  @ 0
    // OF:  8*32*64*64 float2 =  8 MiB  @ 8 MiB
    // V : 8*256*32*64 float2 = 32 MiB  @ 16 MiB (A aliases V)
    // Tf: 256*64 float2 = 128 KiB @ 48 MiB ; Ti: 128 KiB after
    float2* U  = (float2*)(ws);
    float2* OF = (float2*)(ws + 8388608);
    float2* V  = (float2*)(ws + 16777216);
    float2* A  = V;
    float2* Tf = (float2*)(ws + 50331648);
    float2* Ti = (float2*)(ws + 50331648 + 131072);

    k_tw<<<64, 256, 0, stream>>>(Tf, Ti);
    k_fwd_y<<<BB * HH, 256, 0, stream>>>(u, V);
    k_fwd_x<<<512, 256, 0, stream>>>(Tf, V, U);
    k_modew<<<512, 256, 0, stream>>>(wpr, wpi, wnr, wni, U, OF);
    k_inv_x<<<1024, 256, 0, stream>>>(Ti, OF, A);
    k_inv_y<<<BB * HH, 256, 0, stream>>>(A, out);
}

// Round 4
// 274.435 us; speedup vs baseline: 1.7854x; 1.0853x over previous
//
#include <hip/hip_runtime.h>
#include <math.h>

// Sizes fixed by the problem.
#define BB 8
#define HH 256
#define WW 256
#define CC 64
// modes: kx in {0..31} u {224..255} (64 total), ky in {0..31}

__device__ inline void build_tw(float2* tw) {
    // tw[t] = (cos(2*pi*t/256), sin(2*pi*t/256))
    for (int t = threadIdx.x; t < 256; t += blockDim.x) {
        float ang = (float)t * (6.283185307179586f / 256.0f);
        float s, c;
        sincosf(ang, &s, &c);
        tw[t] = make_float2(c, s);
    }
}

__device__ inline void cmac(float2& a, float tx, float ty, float2 v) {
    a.x += tx * v.x - ty * v.y;
    a.y += tx * v.y + ty * v.x;
}

// ---------------------------------------------------------------------------
// K0: twiddle tables.
// Tf[x][j] = e^{-2pi i kxa(j) x/256}            (forward x-DFT operand)
// Ti[j][x] = (2/65536) e^{+2pi i kxa(j) x/256}  (inverse x-DFT operand,
//            hermitian factor 2 + irfft norm folded in; ky==0 fixes up 0.5x)
// kxa(j) = j (j<32) else j+192.  Note parity(kxa(j)) == parity(j).
// ---------------------------------------------------------------------------
__global__ __launch_bounds__(256) void k_tw(float2* __restrict__ Tf,
                                            float2* __restrict__ Ti) {
    int e = blockIdx.x * 256 + threadIdx.x;   // 0..16383
    int x = e >> 6;
    int j = e & 63;
    int kxa = j + ((j >> 5) * 192);
    int tt = (kxa * x) & 255;
    float ang = (float)tt * (6.283185307179586f / 256.0f);
    float s, c;
    sincosf(ang, &s, &c);
    Tf[(size_t)x * 64 + j] = make_float2(c, -s);
    const float k = 2.0f / 65536.0f;
    Ti[(size_t)j * 256 + x] = make_float2(c * k, s * k);
}

// ---------------------------------------------------------------------------
// K1: V[b][x][ky*64+i] = sum_y u[b,x,y,i] * e^{-2pi i ky y/256}
// Radix-2 in y (even/odd ky on u[y]±u[y+128]), u row staged in LDS,
// per-ky padded twiddle table. grid = B*H, 256 threads.
// At HBM-read roofline (~98%): do not touch.
// ---------------------------------------------------------------------------
__global__ __launch_bounds__(256) void k_fwd_y(const float* __restrict__ u,
                                               float2* __restrict__ V) {
    __shared__ float ue[32 * 68];
    __shared__ float uo[32 * 68];
    __shared__ float2 twk[32 * 129];   // aliased as vtile[32*65] in epilogue

    int tid = threadIdx.x;

    #pragma unroll
    for (int k = 0; k < 16; ++k) {
        int e = tid + 256 * k;
        int kyy = e >> 7, y = e & 127;
        int t = (kyy * y) & 255;
        float ang = (float)t * (6.283185307179586f / 256.0f);
        float s, c;
        sincosf(ang, &s, &c);
        twk[kyy * 129 + y] = make_float2(c, s);
    }

    int b = blockIdx.x >> 8;
    int x = blockIdx.x & 255;
    int ky = tid & 31;
    int i0 = (tid >> 5) * 8;
    int yy = tid >> 3;
    int c0 = (tid & 7) * 8;

    const float* ub = u + ((size_t)(b * HH + x)) * (WW * CC);

    float ar[8], ai[8];
    #pragma unroll
    for (int c = 0; c < 8; ++c) { ar[c] = 0.f; ai[c] = 0.f; }

    const float* rbase = (ky & 1) ? uo : ue;
    const float2* tk = twk + ky * 129;

    for (int yt = 0; yt < 4; ++yt) {
        const float* plo = ub + (size_t)(yt * 32 + yy) * CC + c0;
        const float* phi = plo + 128 * CC;
        float4 l0 = *(const float4*)(plo);
        float4 l1 = *(const float4*)(plo + 4);
        float4 h0 = *(const float4*)(phi);
        float4 h1 = *(const float4*)(phi + 4);

        __syncthreads();
        int wb = yy * 68 + c0;
        *(float4*)(ue + wb)     = make_float4(l0.x + h0.x, l0.y + h0.y, l0.z + h0.z, l0.w + h0.w);
        *(float4*)(ue + wb + 4) = make_float4(l1.x + h1.x, l1.y + h1.y, l1.z + h1.z, l1.w + h1.w);
        *(float4*)(uo + wb)     = make_float4(l0.x - h0.x, l0.y - h0.y, l0.z - h0.z, l0.w - h0.w);
        *(float4*)(uo + wb + 4) = make_float4(l1.x - h1.x, l1.y - h1.y, l1.z - h1.z, l1.w - h1.w);
        __syncthreads();

        #pragma unroll
        for (int y2 = 0; y2 < 32; ++y2) {
            int y = yt * 32 + y2;
            const float* s8 = rbase + y2 * 68 + i0;
            float2 cs = tk[y];
            #pragma unroll
            for (int c = 0; c < 8; ++c) {
                float v = s8[c];
                ar[c] += v * cs.x;
                ai[c] -= v * cs.y;
            }
        }
    }

    __syncthreads();
    float2* vtile = twk;
    #pragma unroll
    for (int c = 0; c < 8; ++c)
        vtile[ky * 65 + i0 + c] = make_float2(ar[c], ai[c]);
    __syncthreads();

    float2* vp = V + (size_t)(b * HH + x) * 2048;
    #pragma unroll
    for (int k = 0; k < 8; ++k) {
        int e = tid + 256 * k;
        vp[e] = vtile[(e >> 6) * 65 + (e & 63)];
    }
}

// ---------------------------------------------------------------------------
// K2 (radix-2 GEMM): U[j][ky][b][i] = sum_{x<128} Tf[x][j] *
//                    (V[b][x][ky][i] + (-1)^j V[b][x+128][ky][i])
// grid = 1024: bx = jq + 4*(ky + 32*b). 256 threads.
// thread: jr = t>>5 (j = jq*16+jr, jq*16+jr+8 — same parity), ir = t&31
// (i = ir, ir+32). Planar re/im LDS (cross-parity b32 reads 2-way = free).
// ---------------------------------------------------------------------------
__global__ __launch_bounds__(256) void k_fwd_x(const float2* __restrict__ Tf,
                                               const float2* __restrict__ V,
                                               float2* __restrict__ U) {
    __shared__ float sRe[2 * 2048];   // [par][xx*64+i] 16 KB
    __shared__ float sIm[2 * 2048];   // 16 KB
    __shared__ float2 Ts[32 * 16];    // [xx][jj] 4 KB

    int bx = blockIdx.x;
    int jq = bx & 3;
    int ky = (bx >> 2) & 31;
    int b  = bx >> 7;
    int t = threadIdx.x;
    int jr = t >> 5;      // 0..7
    int ir = t & 31;      // 0..31

    float2 a00 = {0,0}, a01 = {0,0}, a10 = {0,0}, a11 = {0,0};

    const float2* vb = V + (size_t)b * (HH * 2048) + ky * 64;
    int vrow = t >> 3;          // 0..31
    int vcol = (t & 7) * 8;     // complex index
    int tjj = (t & 7) * 2;      // 0..14
    int parOff = (jr & 1) * 2048;

    for (int x0 = 0; x0 < 128; x0 += 32) {
        const float2* plo = vb + (size_t)(x0 + vrow) * 2048 + vcol;
        const float2* phi = plo + 128 * 2048;
        float4 l0 = *(const float4*)(plo);
        float4 l1 = *(const float4*)(plo + 2);
        float4 l2 = *(const float4*)(plo + 4);
        float4 l3 = *(const float4*)(plo + 6);
        float4 h0 = *(const float4*)(phi);
        float4 h1 = *(const float4*)(phi + 2);
        float4 h2 = *(const float4*)(phi + 4);
        float4 h3 = *(const float4*)(phi + 6);
        float4 tv = *(const float4*)(Tf + (size_t)(x0 + vrow) * 64 + jq * 16 + tjj);

        __syncthreads();   // previous tile's LDS reads complete
        *(float4*)&Ts[vrow * 16 + tjj] = tv;
        int wb = vrow * 64 + vcol;
        *(float4*)(sRe + wb)            = make_float4(l0.x+h0.x, l0.z+h0.z, l1.x+h1.x, l1.z+h1.z);
        *(float4*)(sRe + wb + 4)        = make_float4(l2.x+h2.x, l2.z+h2.z, l3.x+h3.x, l3.z+h3.z);
        *(float4*)(sIm + wb)            = make_float4(l0.y+h0.y, l0.w+h0.w, l1.y+h1.y, l1.w+h1.w);
        *(float4*)(sIm + wb + 4)        = make_float4(l2.y+h2.y, l2.w+h2.w, l3.y+h3.y, l3.w+h3.w);
        *(float4*)(sRe + 2048 + wb)     = make_float4(l0.x-h0.x, l0.z-h0.z, l1.x-h1.x, l1.z-h1.z);
        *(float4*)(sRe + 2048 + wb + 4) = make_float4(l2.x-h2.x, l2.z-h2.z, l3.x-h3.x, l3.z-h3.z);
        *(float4*)(sIm + 2048 + wb)     = make_float4(l0.y-h0.y, l0.w-h0.w, l1.y-h1.y, l1.w-h1.w);
        *(float4*)(sIm + 2048 + wb + 4) = make_float4(l2.y-h2.y, l2.w-h2.w, l3.y-h3.y, l3.w-h3.w);
        __syncthreads();

        #pragma unroll
        for (int xx = 0; xx < 32; ++xx) {
            float2 t0 = Ts[xx * 16 + jr];
            float2 t1 = Ts[xx * 16 + jr + 8];
            const float* re = sRe + parOff + xx * 64;
            const float* im = sIm + parOff + xx * 64;
            float vr0 = re[ir], vr1 = re[ir + 32];
            float vi0 = im[ir], vi1 = im[ir + 32];
            a00.x += t0.x*vr0 - t0.y*vi0;  a00.y += t0.x*vi0 + t0.y*vr0;
            a01.x += t0.x*vr1 - t0.y*vi1;  a01.y += t0.x*vi1 + t0.y*vr1;
            a10.x += t1.x*vr0 - t1.y*vi0;  a10.y += t1.x*vi0 + t1.y*vr0;
            a11.x += t1.x*vr1 - t1.y*vi1;  a11.y += t1.x*vi1 + t1.y*vr1;
        }
    }

    int j0 = jq * 16 + jr;
    float2* u0 = U + ((size_t)(j0 * 32 + ky) * 8 + b) * 64 + ir;
    u0[0]  = a00;
    u0[32] = a01;
    float2* u1 = U + ((size_t)((j0 + 8) * 32 + ky) * 8 + b) * 64 + ir;
    u1[0]  = a10;
    u1[32] = a11;
}

// ---------------------------------------------------------------------------
// K3 (fused weight-transpose + mode mul):
// OF[b][ky][j][o] = sum_i U[j][ky][b][i] * (wr[i,o,kxl,ky], wi[i,o,kxl,ky])
// grid = 1024: bx = j + 64*kyt + 512*oh  (kyt 0..7 -> 4 ky; oh 0..1 -> 32 o).
// Blocks sharing a weight cache line are 64*k apart in blockIdx -> same XCD.
// ---------------------------------------------------------------------------
__global__ __launch_bounds__(256) void k_modew(const float* __restrict__ wpr,
                                               const float* __restrict__ wpi,
                                               const float* __restrict__ wnr,
                                               const float* __restrict__ wni,
                                               const float2* __restrict__ U,
                                               float2* __restrict__ OF) {
    __shared__ float2 uS[4 * 8 * 64];   // [kyr][b][i]    16 KB
    __shared__ float2 wS[4 * 8 * 32];   // [kyr][ir][o32]  8 KB (per i-tile)

    int bx = blockIdx.x;
    int j   = bx & 63;
    int kyt = (bx >> 6) & 7;
    int oh  = bx >> 9;
    int ky0 = kyt * 4;
    int sel = j >> 5, kxl = j & 31;
    const float* sr = sel ? wnr : wpr;
    const float* si = sel ? wni : wpi;
    int tid = threadIdx.x;

    const float2* up = U + (size_t)(j * 32 + ky0) * 512;
    #pragma unroll
    for (int k = 0; k < 8; ++k) uS[tid + 256 * k] = up[tid + 256 * k];

    int o32 = tid & 31;
    int bh  = tid >> 5;
    int irS = tid >> 5;
    int ooS = tid & 31;

    float2 acc[4];
    #pragma unroll
    for (int k = 0; k < 4; ++k) acc[k] = make_float2(0.f, 0.f);

    for (int it = 0; it < 8; ++it) {
        __syncthreads();  // uS ready (it==0) / wS reads of prev tile done
        {
            int ig = it * 8 + irS;
            int og = oh * 32 + ooS;
            size_t base = (((size_t)(ig * 64 + og)) * 32 + kxl) * 32 + ky0;
            float4 r0 = *(const float4*)(sr + base);
            float4 q0 = *(const float4*)(si + base);
            float2* wrow = wS + irS * 32 + ooS;
            wrow[0 * 256] = make_float2(r0.x, q0.x);
            wrow[1 * 256] = make_float2(r0.y, q0.y);
            wrow[2 * 256] = make_float2(r0.z, q0.z);
            wrow[3 * 256] = make_float2(r0.w, q0.w);
        }
        __syncthreads();
        #pragma unroll
        for (int ir = 0; ir < 8; ++ir) {
            int ig = it * 8 + ir;
            #pragma unroll
            for (int ky = 0; ky < 4; ++ky) {
                float2 wv = wS[ky * 256 + ir * 32 + o32];
                float2 uv = uS[ky * 512 + bh * 64 + ig];
                acc[ky].x += uv.x * wv.x - uv.y * wv.y;
                acc[ky].y += uv.x * wv.y + uv.y * wv.x;
            }
        }
    }

    int og = oh * 32 + o32;
    #pragma unroll
    for (int ky = 0; ky < 4; ++ky) {
        OF[((size_t)(bh * 32 + ky0 + ky) * 64 + j) * 64 + og] = acc[ky];
    }
}

// ---------------------------------------------------------------------------
// K4 (radix-2 GEMM): for x<128:
//   Se = sum_{even j} Ti[j][x] OF[b][ky][j][o], So = sum_{odd j} ...
//   A[b][x]     = (Se+So)*sc,  A[b][x+128] = (Se-So)*sc   (sc: ky==0 -> 0.5)
// grid = 1024: bx = xt + 4*(ky + 32*b). 256 threads.
// thread: xr = t>>4 (xp = xt*32+xr*2+{0,1}), or = t&15 (o = or+16q).
// ---------------------------------------------------------------------------
__global__ __launch_bounds__(256) void k_inv_x(const float2* __restrict__ Ti,
                                               const float2* __restrict__ OF,
                                               float2* __restrict__ A) {
    __shared__ float2 Ts[32 * 32];   // [jj][xp]  8 KB
    __shared__ float2 Os[32 * 64];   // [jj][o]  16 KB

    int bx = blockIdx.x;
    int xt = bx & 3;
    int ky = (bx >> 2) & 31;
    int b  = bx >> 7;
    int t = threadIdx.x;
    int or_ = t & 15;
    int xr = t >> 4;     // 0..15

    float2 acc[2][2][4];   // [parity][p][q]
    #pragma unroll
    for (int pa = 0; pa < 2; ++pa)
        #pragma unroll
        for (int p = 0; p < 2; ++p)
            #pragma unroll
            for (int q = 0; q < 4; ++q) acc[pa][p][q] = make_float2(0.f, 0.f);

    const float2* ofb = OF + (size_t)(b * 32 + ky) * 4096;
    int sj = t >> 3;         // 0..31
    int sx = (t & 7) * 4;    // Ts cols (4 complex)
    int so = (t & 7) * 8;    // Os cols (8 complex)

    for (int kh = 0; kh < 2; ++kh) {
        const float2* tsrc = Ti + (size_t)(kh * 32 + sj) * 256 + xt * 32 + sx;
        float4 t0 = *(const float4*)(tsrc);
        float4 t1 = *(const float4*)(tsrc + 2);
        const float2* osrc = ofb + (size_t)(kh * 32 + sj) * 64 + so;
        float4 o0 = *(const float4*)(osrc);
        float4 o1 = *(const float4*)(osrc + 2);
        float4 o2 = *(const float4*)(osrc + 4);
        float4 o3 = *(const float4*)(osrc + 6);

        __syncthreads();
        *(float4*)&Ts[sj * 32 + sx]     = t0;
        *(float4*)&Ts[sj * 32 + sx + 2] = t1;
        float2* od = &Os[sj * 64 + so];
        *(float4*)(od)     = o0;
        *(float4*)(od + 2) = o1;
        *(float4*)(od + 4) = o2;
        *(float4*)(od + 6) = o3;
        __syncthreads();

        #pragma unroll
        for (int jj = 0; jj < 32; ++jj) {
            float4 tp = *(const float4*)&Ts[jj * 32 + xr * 2];
            float2 q0 = Os[jj * 64 + or_];
            float2 q1 = Os[jj * 64 + or_ + 16];
            float2 q2 = Os[jj * 64 + or_ + 32];
            float2 q3 = Os[jj * 64 + or_ + 48];
            const int pa = jj & 1;     // constant after unroll
            cmac(acc[pa][0][0], tp.x, tp.y, q0);
            cmac(acc[pa][0][1], tp.x, tp.y, q1);
            cmac(acc[pa][0][2], tp.x, tp.y, q2);
            cmac(acc[pa][0][3], tp.x, tp.y, q3);
            cmac(acc[pa][1][0], tp.z, tp.w, q0);
            cmac(acc[pa][1][1], tp.z, tp.w, q1);
            cmac(acc[pa][1][2], tp.z, tp.w, q2);
            cmac(acc[pa][1][3], tp.z, tp.w, q3);
        }
    }

    float sc = (ky == 0) ? 0.5f : 1.0f;
    #pragma unroll
    for (int p = 0; p < 2; ++p) {
        int x = xt * 32 + xr * 2 + p;
        float2* alo = A + ((size_t)(b * 256 + x) * 32 + ky) * 64 + or_;
        float2* ahi = A + ((size_t)(b * 256 + x + 128) * 32 + ky) * 64 + or_;
        #pragma unroll
        for (int q = 0; q < 4; ++q) {
            float2 se = acc[0][p][q], so2 = acc[1][p][q];
            alo[16 * q] = make_float2((se.x + so2.x) * sc, (se.y + so2.y) * sc);
            ahi[16 * q] = make_float2((se.x - so2.x) * sc, (se.y - so2.y) * sc);
        }
    }
}

// ---------------------------------------------------------------------------
// K5: out[b,x,y,o] = sum_ky ( A.re*cos(2pi ky y/256) - A.im*sin(...) )
// y/y+128 parity split. grid = B*H, 256 threads. Near HBM-write floor.
// ---------------------------------------------------------------------------
__global__ __launch_bounds__(256) void k_inv_y(const float2* __restrict__ A,
                                               float* __restrict__ out) {
    __shared__ float2 tw[256];
    build_tw(tw);

    int b = blockIdx.x >> 8;
    int x = blockIdx.x & 255;
    int tid = threadIdx.x;
    int o2 = tid & 31;
    int w = tid >> 5; // 0..7

    const float2* ap = A + (size_t)(b * 256 + x) * 32 * 64;
    float2 a_lo[32], a_hi[32];
    #pragma unroll
    for (int ky = 0; ky < 32; ++ky) {
        a_lo[ky] = ap[ky * 64 + o2];
        a_hi[ky] = ap[ky * 64 + o2 + 32];
    }
    __syncthreads();

    float* op = out + (size_t)(b * 256 + x) * (256 * 64);
    for (int p = w * 16; p < w * 16 + 16; ++p) {
        float se0 = 0.f, so0 = 0.f, se1 = 0.f, so1 = 0.f;
        #pragma unroll
        for (int ky = 0; ky < 32; ky += 2) {
            float2 cs0 = tw[(ky * p) & 255];
            se0 += a_lo[ky].x * cs0.x - a_lo[ky].y * cs0.y;
            se1 += a_hi[ky].x * cs0.x - a_hi[ky].y * cs0.y;
            float2 cs1 = tw[((ky + 1) * p) & 255];
            so0 += a_lo[ky + 1].x * cs1.x - a_lo[ky + 1].y * cs1.y;
            so1 += a_hi[ky + 1].x * cs1.x - a_hi[ky + 1].y * cs1.y;
        }
        op[p * 64 + o2]              = se0 + so0;
        op[p * 64 + o2 + 32]         = se1 + so1;
        op[(p + 128) * 64 + o2]      = se0 - so0;
        op[(p + 128) * 64 + o2 + 32] = se1 - so1;
    }
}

// ---------------------------------------------------------------------------
extern "C" void kernel_launch(void* const* d_in, const int* in_sizes, int n_in,
                              void* d_out, int out_size, void* d_ws, size_t ws_size,
                              hipStream_t stream) {
    const float* u   = (const float*)d_in[0];
    const float* wpr = (const float*)d_in[1];
    const float* wpi = (const float*)d_in[2];
    const float* wnr = (const float*)d_in[3];
    const float* wni = (const float*)d_in[4];
    float* out = (float*)d_out;

    char* ws = (char*)d_ws;
    // U : 64*32*8*64  float2 =  8 MiB  @ 0
    // OF:  8*32*64*64 float2 =  8 MiB  @ 8 MiB
    // V : 8*256*32*64 float2 = 32 MiB  @ 16 MiB (A aliases V)
    // Tf: 256*64 float2 = 128 KiB @ 48 MiB ; Ti: 128 KiB after
    float2* U  = (float2*)(ws);
    float2* OF = (float2*)(ws + 8388608);
    float2* V  = (float2*)(ws + 16777216);
    float2* A  = V;
    float2* Tf = (float2*)(ws + 50331648);
    float2* Ti = (float2*)(ws + 50331648 + 131072);

    k_tw<<<64, 256, 0, stream>>>(Tf, Ti);
    k_fwd_y<<<BB * HH, 256, 0, stream>>>(u, V);
    k_fwd_x<<<1024, 256, 0, stream>>>(Tf, V, U);
    k_modew<<<1024, 256, 0, stream>>>(wpr, wpi, wnr, wni, U, OF);
    k_inv_x<<<1024, 256, 0, stream>>>(Ti, OF, A);
    k_inv_y<<<BB * HH, 256, 0, stream>>>(A, out);
}

// Round 5
// 226.565 us; speedup vs baseline: 2.1627x; 1.2113x over previous
//
#include <hip/hip_runtime.h>
#include <math.h>

// Sizes fixed by the problem.
#define BB 8
#define HH 256
#define WW 256
#define CC 64
// modes: kx in {0..31} u {224..255} (64 total), ky in {0..31}

__device__ inline void cmac(float2& a, float tx, float ty, float2 v) {
    a.x += tx * v.x - ty * v.y;
    a.y += tx * v.y + ty * v.x;
}

// ---------------------------------------------------------------------------
// K0: all twiddle tables (one kernel, 128 blocks x 256).
// Tf[x][j]  = e^{-2pi i kxa(j) x/256}                       (fwd x-DFT)
// Ti[j][x]  = (2/65536) e^{+2pi i kxa(j) x/256}             (inv x-DFT)
// Ty[y'][par*32+cs*16+m]: cs=0 -> cos(2pi ky y'/256), cs=1 -> -sin(...),
//                         ky = 2m+par                        (fwd y-DFT)
// T2[(pi*32+j)*128+p]: j=2m+ri; ri=0 -> cos(2pi ky p/256), ri=1 -> -sin(...),
//                         ky = 2m+pi                         (inv y-DFT)
// kxa(j) = j (j<32) else j+192.  parity(kxa(j)) == parity(j).
// ---------------------------------------------------------------------------
__global__ __launch_bounds__(256) void k_tw(float2* __restrict__ Tf,
                                            float2* __restrict__ Ti,
                                            float* __restrict__ Ty,
                                            float* __restrict__ T2) {
    int e = blockIdx.x * 256 + threadIdx.x;   // 0..32767
    if (e < 16384) {
        int x = e >> 6;
        int j = e & 63;
        int kxa = j + ((j >> 5) * 192);
        int tt = (kxa * x) & 255;
        float ang = (float)tt * (6.283185307179586f / 256.0f);
        float s, c;
        sincosf(ang, &s, &c);
        Tf[(size_t)x * 64 + j] = make_float2(c, -s);
        const float k = 2.0f / 65536.0f;
        Ti[(size_t)j * 256 + x] = make_float2(c * k, s * k);
    } else {
        int f = e - 16384;
        if (f < 8192) {
            int yp = f >> 6;
            int col = f & 63;
            int par = (col >> 5) & 1;
            int cs = (col >> 4) & 1;
            int m = col & 15;
            int ky = 2 * m + par;
            int tt = (ky * yp) & 255;
            float ang = (float)tt * (6.283185307179586f / 256.0f);
            float s, c;
            sincosf(ang, &s, &c);
            Ty[f] = cs ? -s : c;
        } else {
            int g = f - 8192;
            int pi = g >> 12;
            int j = (g >> 7) & 31;
            int p = g & 127;
            int m = j >> 1, ri = j & 1;
            int ky = 2 * m + pi;
            int tt = (ky * p) & 255;
            float ang = (float)tt * (6.283185307179586f / 256.0f);
            float s, c;
            sincosf(ang, &s, &c);
            T2[g] = ri ? -s : c;
        }
    }
}

// ---------------------------------------------------------------------------
// K1 (GEMM form): V[b][x][ky][i] = sum_{y'<128} Ty[y'][ky-col] *
//                 (u[y'] + (-1)^ky u[y'+128])[i]
// grid = B*H (one (b,x) row), 256 threads.
// thread: w = t>>4: p = w&1 (ky parity), kyq = w>>1 -> ky = 4kyq+2d+p, d 0..1;
//         i4 = (t&15)*4 -> 4 channels.
// K tiled by 32 y'; u butterflied + Ty tile staged in LDS (68-float pitch:
// staging writes & plane reads conflict-free; T reads broadcast).
// ---------------------------------------------------------------------------
__global__ __launch_bounds__(256, 6) void k_fwd_y(const float* __restrict__ u,
                                                  const float* __restrict__ Ty,
                                                  float2* __restrict__ V) {
    __shared__ float ue[32 * 68];
    __shared__ float uo[32 * 68];
    __shared__ float Tt[32 * 68];

    int t = threadIdx.x;
    int b = blockIdx.x >> 8;
    int x = blockIdx.x & 255;
    int i4 = (t & 15) * 4;
    int w = t >> 4;
    int p = w & 1;
    int kyq = w >> 1;
    int yy = t >> 3;
    int c0 = (t & 7) * 8;

    const float* ub = u + ((size_t)(b * HH + x)) * (WW * CC);
    const float* uplane = p ? uo : ue;

    float ar0x=0,ar0y=0,ar0z=0,ar0w=0, ai0x=0,ai0y=0,ai0z=0,ai0w=0;
    float ar1x=0,ar1y=0,ar1z=0,ar1w=0, ai1x=0,ai1y=0,ai1z=0,ai1w=0;

    for (int yt = 0; yt < 4; ++yt) {
        const float* plo = ub + (size_t)(yt * 32 + yy) * CC + c0;
        const float* phi = plo + 128 * CC;
        float4 l0 = *(const float4*)(plo);
        float4 l1 = *(const float4*)(plo + 4);
        float4 h0 = *(const float4*)(phi);
        float4 h1 = *(const float4*)(phi + 4);
        const float* tsrc = Ty + (size_t)(yt * 32 + yy) * 64 + c0;
        float4 t0 = *(const float4*)(tsrc);
        float4 t1 = *(const float4*)(tsrc + 4);

        __syncthreads();   // previous tile's LDS reads complete
        int wb = yy * 68 + c0;
        *(float4*)(ue + wb)     = make_float4(l0.x + h0.x, l0.y + h0.y, l0.z + h0.z, l0.w + h0.w);
        *(float4*)(ue + wb + 4) = make_float4(l1.x + h1.x, l1.y + h1.y, l1.z + h1.z, l1.w + h1.w);
        *(float4*)(uo + wb)     = make_float4(l0.x - h0.x, l0.y - h0.y, l0.z - h0.z, l0.w - h0.w);
        *(float4*)(uo + wb + 4) = make_float4(l1.x - h1.x, l1.y - h1.y, l1.z - h1.z, l1.w - h1.w);
        *(float4*)(Tt + wb)     = t0;
        *(float4*)(Tt + wb + 4) = t1;
        __syncthreads();

        #pragma unroll
        for (int y2 = 0; y2 < 32; ++y2) {
            const float* tb = Tt + y2 * 68 + p * 32 + kyq * 2;
            float2 cp = *(const float2*)(tb);        // cos for m = 2kyq, 2kyq+1
            float2 sp = *(const float2*)(tb + 16);   // -sin for same
            float4 uq = *(const float4*)(uplane + y2 * 68 + i4);
            ar0x += cp.x * uq.x; ar0y += cp.x * uq.y; ar0z += cp.x * uq.z; ar0w += cp.x * uq.w;
            ai0x += sp.x * uq.x; ai0y += sp.x * uq.y; ai0z += sp.x * uq.z; ai0w += sp.x * uq.w;
            ar1x += cp.y * uq.x; ar1y += cp.y * uq.y; ar1z += cp.y * uq.z; ar1w += cp.y * uq.w;
            ai1x += sp.y * uq.x; ai1y += sp.y * uq.y; ai1z += sp.y * uq.z; ai1w += sp.y * uq.w;
        }
    }

    // ky = 2*m + p, m = 2kyq + d  ->  ky = 4kyq + 2d + p
    {
        int ky = 4 * kyq + p;
        float2* vp = V + (size_t)(b * HH + x) * 2048 + ky * 64 + i4;
        *(float4*)(vp)     = make_float4(ar0x, ai0x, ar0y, ai0y);
        *(float4*)(vp + 2) = make_float4(ar0z, ai0z, ar0w, ai0w);
    }
    {
        int ky = 4 * kyq + 2 + p;
        float2* vp = V + (size_t)(b * HH + x) * 2048 + ky * 64 + i4;
        *(float4*)(vp)     = make_float4(ar1x, ai1x, ar1y, ai1y);
        *(float4*)(vp + 2) = make_float4(ar1z, ai1z, ar1w, ai1w);
    }
}

// ---------------------------------------------------------------------------
// K2 (radix-2 GEMM): U[j][ky][b][i] = sum_{x<128} Tf[x][j] *
//                    (V[b][x][ky][i] + (-1)^j V[b][x+128][ky][i])
// grid = 1024: bx = jq + 4*(ky + 32*b). 256 threads.
// ---------------------------------------------------------------------------
__global__ __launch_bounds__(256) void k_fwd_x(const float2* __restrict__ Tf,
                                               const float2* __restrict__ V,
                                               float2* __restrict__ U) {
    __shared__ float sRe[2 * 2048];   // [par][xx*64+i] 16 KB
    __shared__ float sIm[2 * 2048];   // 16 KB
    __shared__ float2 Ts[32 * 16];    // [xx][jj] 4 KB

    int bx = blockIdx.x;
    int jq = bx & 3;
    int ky = (bx >> 2) & 31;
    int b  = bx >> 7;
    int t = threadIdx.x;
    int jr = t >> 5;      // 0..7
    int ir = t & 31;      // 0..31

    float2 a00 = {0,0}, a01 = {0,0}, a10 = {0,0}, a11 = {0,0};

    const float2* vb = V + (size_t)b * (HH * 2048) + ky * 64;
    int vrow = t >> 3;          // 0..31
    int vcol = (t & 7) * 8;     // complex index
    int tjj = (t & 7) * 2;      // 0..14
    int parOff = (jr & 1) * 2048;

    for (int x0 = 0; x0 < 128; x0 += 32) {
        const float2* plo = vb + (size_t)(x0 + vrow) * 2048 + vcol;
        const float2* phi = plo + 128 * 2048;
        float4 l0 = *(const float4*)(plo);
        float4 l1 = *(const float4*)(plo + 2);
        float4 l2 = *(const float4*)(plo + 4);
        float4 l3 = *(const float4*)(plo + 6);
        float4 h0 = *(const float4*)(phi);
        float4 h1 = *(const float4*)(phi + 2);
        float4 h2 = *(const float4*)(phi + 4);
        float4 h3 = *(const float4*)(phi + 6);
        float4 tv = *(const float4*)(Tf + (size_t)(x0 + vrow) * 64 + jq * 16 + tjj);

        __syncthreads();   // previous tile's LDS reads complete
        *(float4*)&Ts[vrow * 16 + tjj] = tv;
        int wb = vrow * 64 + vcol;
        *(float4*)(sRe + wb)            = make_float4(l0.x+h0.x, l0.z+h0.z, l1.x+h1.x, l1.z+h1.z);
        *(float4*)(sRe + wb + 4)        = make_float4(l2.x+h2.x, l2.z+h2.z, l3.x+h3.x, l3.z+h3.z);
        *(float4*)(sIm + wb)            = make_float4(l0.y+h0.y, l0.w+h0.w, l1.y+h1.y, l1.w+h1.w);
        *(float4*)(sIm + wb + 4)        = make_float4(l2.y+h2.y, l2.w+h2.w, l3.y+h3.y, l3.w+h3.w);
        *(float4*)(sRe + 2048 + wb)     = make_float4(l0.x-h0.x, l0.z-h0.z, l1.x-h1.x, l1.z-h1.z);
        *(float4*)(sRe + 2048 + wb + 4) = make_float4(l2.x-h2.x, l2.z-h2.z, l3.x-h3.x, l3.z-h3.z);
        *(float4*)(sIm + 2048 + wb)     = make_float4(l0.y-h0.y, l0.w-h0.w, l1.y-h1.y, l1.w-h1.w);
        *(float4*)(sIm + 2048 + wb + 4) = make_float4(l2.y-h2.y, l2.w-h2.w, l3.y-h3.y, l3.w-h3.w);
        __syncthreads();

        #pragma unroll
        for (int xx = 0; xx < 32; ++xx) {
            float2 t0 = Ts[xx * 16 + jr];
            float2 t1 = Ts[xx * 16 + jr + 8];
            const float* re = sRe + parOff + xx * 64;
            const float* im = sIm + parOff + xx * 64;
            float vr0 = re[ir], vr1 = re[ir + 32];
            float vi0 = im[ir], vi1 = im[ir + 32];
            a00.x += t0.x*vr0 - t0.y*vi0;  a00.y += t0.x*vi0 + t0.y*vr0;
            a01.x += t0.x*vr1 - t0.y*vi1;  a01.y += t0.x*vi1 + t0.y*vr1;
            a10.x += t1.x*vr0 - t1.y*vi0;  a10.y += t1.x*vi0 + t1.y*vr0;
            a11.x += t1.x*vr1 - t1.y*vi1;  a11.y += t1.x*vi1 + t1.y*vr1;
        }
    }

    int j0 = jq * 16 + jr;
    float2* u0 = U + ((size_t)(j0 * 32 + ky) * 8 + b) * 64 + ir;
    u0[0]  = a00;
    u0[32] = a01;
    float2* u1 = U + ((size_t)((j0 + 8) * 32 + ky) * 8 + b) * 64 + ir;
    u1[0]  = a10;
    u1[32] = a11;
}

// ---------------------------------------------------------------------------
// K3 (fused weight-transpose + mode mul):
// OF[b][ky][j][o] = sum_i U[j][ky][b][i] * (wr[i,o,kxl,ky], wi[i,o,kxl,ky])
// grid = 1024: bx = j + 64*kyt + 512*oh  (kyt 0..7 -> 4 ky; oh 0..1 -> 32 o).
// ---------------------------------------------------------------------------
__global__ __launch_bounds__(256) void k_modew(const float* __restrict__ wpr,
                                               const float* __restrict__ wpi,
                                               const float* __restrict__ wnr,
                                               const float* __restrict__ wni,
                                               const float2* __restrict__ U,
                                               float2* __restrict__ OF) {
    __shared__ float2 uS[4 * 8 * 64];   // [kyr][b][i]    16 KB
    __shared__ float2 wS[4 * 8 * 32];   // [kyr][ir][o32]  8 KB (per i-tile)

    int bx = blockIdx.x;
    int j   = bx & 63;
    int kyt = (bx >> 6) & 7;
    int oh  = bx >> 9;
    int ky0 = kyt * 4;
    int sel = j >> 5, kxl = j & 31;
    const float* sr = sel ? wnr : wpr;
    const float* si = sel ? wni : wpi;
    int tid = threadIdx.x;

    const float2* up = U + (size_t)(j * 32 + ky0) * 512;
    #pragma unroll
    for (int k = 0; k < 8; ++k) uS[tid + 256 * k] = up[tid + 256 * k];

    int o32 = tid & 31;
    int bh  = tid >> 5;
    int irS = tid >> 5;
    int ooS = tid & 31;

    float2 acc[4];
    #pragma unroll
    for (int k = 0; k < 4; ++k) acc[k] = make_float2(0.f, 0.f);

    for (int it = 0; it < 8; ++it) {
        __syncthreads();  // uS ready (it==0) / wS reads of prev tile done
        {
            int ig = it * 8 + irS;
            int og = oh * 32 + ooS;
            size_t base = (((size_t)(ig * 64 + og)) * 32 + kxl) * 32 + ky0;
            float4 r0 = *(const float4*)(sr + base);
            float4 q0 = *(const float4*)(si + base);
            float2* wrow = wS + irS * 32 + ooS;
            wrow[0 * 256] = make_float2(r0.x, q0.x);
            wrow[1 * 256] = make_float2(r0.y, q0.y);
            wrow[2 * 256] = make_float2(r0.z, q0.z);
            wrow[3 * 256] = make_float2(r0.w, q0.w);
        }
        __syncthreads();
        #pragma unroll
        for (int ir = 0; ir < 8; ++ir) {
            int ig = it * 8 + ir;
            #pragma unroll
            for (int ky = 0; ky < 4; ++ky) {
                float2 wv = wS[ky * 256 + ir * 32 + o32];
                float2 uv = uS[ky * 512 + bh * 64 + ig];
                acc[ky].x += uv.x * wv.x - uv.y * wv.y;
                acc[ky].y += uv.x * wv.y + uv.y * wv.x;
            }
        }
    }

    int og = oh * 32 + o32;
    #pragma unroll
    for (int ky = 0; ky < 4; ++ky) {
        OF[((size_t)(bh * 32 + ky0 + ky) * 64 + j) * 64 + og] = acc[ky];
    }
}

// ---------------------------------------------------------------------------
// K4 (radix-2 GEMM): for x<128:
//   Se = sum_{even j} Ti[j][x] OF[b][ky][j][o], So = sum_{odd j} ...
//   A[b][x]     = (Se+So)*sc,  A[b][x+128] = (Se-So)*sc   (sc: ky==0 -> 0.5)
// grid = 1024: bx = xt + 4*(ky + 32*b). 256 threads.
// ---------------------------------------------------------------------------
__global__ __launch_bounds__(256) void k_inv_x(const float2* __restrict__ Ti,
                                               const float2* __restrict__ OF,
                                               float2* __restrict__ A) {
    __shared__ float2 Ts[32 * 32];   // [jj][xp]  8 KB
    __shared__ float2 Os[32 * 64];   // [jj][o]  16 KB

    int bx = blockIdx.x;
    int xt = bx & 3;
    int ky = (bx >> 2) & 31;
    int b  = bx >> 7;
    int t = threadIdx.x;
    int or_ = t & 15;
    int xr = t >> 4;     // 0..15

    float2 acc[2][2][4];   // [parity][p][q]
    #pragma unroll
    for (int pa = 0; pa < 2; ++pa)
        #pragma unroll
        for (int p = 0; p < 2; ++p)
            #pragma unroll
            for (int q = 0; q < 4; ++q) acc[pa][p][q] = make_float2(0.f, 0.f);

    const float2* ofb = OF + (size_t)(b * 32 + ky) * 4096;
    int sj = t >> 3;         // 0..31
    int sx = (t & 7) * 4;    // Ts cols (4 complex)
    int so = (t & 7) * 8;    // Os cols (8 complex)

    for (int kh = 0; kh < 2; ++kh) {
        const float2* tsrc = Ti + (size_t)(kh * 32 + sj) * 256 + xt * 32 + sx;
        float4 t0 = *(const float4*)(tsrc);
        float4 t1 = *(const float4*)(tsrc + 2);
        const float2* osrc = ofb + (size_t)(kh * 32 + sj) * 64 + so;
        float4 o0 = *(const float4*)(osrc);
        float4 o1 = *(const float4*)(osrc + 2);
        float4 o2 = *(const float4*)(osrc + 4);
        float4 o3 = *(const float4*)(osrc + 6);

        __syncthreads();
        *(float4*)&Ts[sj * 32 + sx]     = t0;
        *(float4*)&Ts[sj * 32 + sx + 2] = t1;
        float2* od = &Os[sj * 64 + so];
        *(float4*)(od)     = o0;
        *(float4*)(od + 2) = o1;
        *(float4*)(od + 4) = o2;
        *(float4*)(od + 6) = o3;
        __syncthreads();

        #pragma unroll
        for (int jj = 0; jj < 32; ++jj) {
            float4 tp = *(const float4*)&Ts[jj * 32 + xr * 2];
            float2 q0 = Os[jj * 64 + or_];
            float2 q1 = Os[jj * 64 + or_ + 16];
            float2 q2 = Os[jj * 64 + or_ + 32];
            float2 q3 = Os[jj * 64 + or_ + 48];
            const int pa = jj & 1;     // constant after unroll
            cmac(acc[pa][0][0], tp.x, tp.y, q0);
            cmac(acc[pa][0][1], tp.x, tp.y, q1);
            cmac(acc[pa][0][2], tp.x, tp.y, q2);
            cmac(acc[pa][0][3], tp.x, tp.y, q3);
            cmac(acc[pa][1][0], tp.z, tp.w, q0);
            cmac(acc[pa][1][1], tp.z, tp.w, q1);
            cmac(acc[pa][1][2], tp.z, tp.w, q2);
            cmac(acc[pa][1][3], tp.z, tp.w, q3);
        }
    }

    float sc = (ky == 0) ? 0.5f : 1.0f;
    #pragma unroll
    for (int p = 0; p < 2; ++p) {
        int x = xt * 32 + xr * 2 + p;
        float2* alo = A + ((size_t)(b * 256 + x) * 32 + ky) * 64 + or_;
        float2* ahi = A + ((size_t)(b * 256 + x + 128) * 32 + ky) * 64 + or_;
        #pragma unroll
        for (int q = 0; q < 4; ++q) {
            float2 se = acc[0][p][q], so2 = acc[1][p][q];
            alo[16 * q] = make_float2((se.x + so2.x) * sc, (se.y + so2.y) * sc);
            ahi[16 * q] = make_float2((se.x - so2.x) * sc, (se.y - so2.y) * sc);
        }
    }
}

// ---------------------------------------------------------------------------
// K5 (GEMM form): per (b,x):
//   S_pi[p][o] = sum_j T2[pi][j][p] * A'[pi][j][o]   (j = 16m x {re,im}, K=32)
//   out[p][o] = S_0+S_1 ; out[p+128][o] = S_0-S_1    (p in [0,128))
// grid = B*H, 256 threads: o4 = (t&15)*4 (4 o), pr = t>>4 (8 p: pr*8..+7).
// A' staged planar once (16 KB); T2 staged in 4 j-tiles ([2][8][132] pitch).
// ---------------------------------------------------------------------------
__global__ __launch_bounds__(256, 4) void k_inv_y(const float* __restrict__ T2g,
                                                  const float2* __restrict__ A,
                                                  float* __restrict__ out) {
    __shared__ float As[2 * 32 * 64];    // [pi][j][o]       16 KB
    __shared__ float T2s[2 * 8 * 132];   // [pi][jj][p]+pad  8.25 KB

    int t = threadIdx.x;
    int b = blockIdx.x >> 8;
    int x = blockIdx.x & 255;
    int o4 = (t & 15) * 4;
    int pr = t >> 4;            // 0..15

    float acc[2][8][4];
    #pragma unroll
    for (int pi = 0; pi < 2; ++pi)
        #pragma unroll
        for (int pp = 0; pp < 8; ++pp)
            #pragma unroll
            for (int k = 0; k < 4; ++k) acc[pi][pp][k] = 0.f;

    // stage A' planar: A[b][x][ky][o] -> As[ky&1][2*(ky>>1)+{re,im}][o]
    {
        int ky = t >> 3, oc = (t & 7) * 8;
        const float2* ap = A + (size_t)(b * 256 + x) * 2048 + ky * 64 + oc;
        float4 g0 = *(const float4*)(ap);
        float4 g1 = *(const float4*)(ap + 2);
        float4 g2 = *(const float4*)(ap + 4);
        float4 g3 = *(const float4*)(ap + 6);
        int pi = ky & 1, m = ky >> 1;
        float* re = As + ((pi * 32) + 2 * m) * 64 + oc;
        float* im = As + ((pi * 32) + 2 * m + 1) * 64 + oc;
        *(float4*)(re)     = make_float4(g0.x, g0.z, g1.x, g1.z);
        *(float4*)(re + 4) = make_float4(g2.x, g2.z, g3.x, g3.z);
        *(float4*)(im)     = make_float4(g0.y, g0.w, g1.y, g1.w);
        *(float4*)(im + 4) = make_float4(g2.y, g2.w, g3.y, g3.w);
    }

    int pi_s = t >> 7;           // 0..1
    int jj_s = (t >> 4) & 7;     // 0..7
    int pc   = (t & 15) * 8;     // 0..120

    for (int jt = 0; jt < 4; ++jt) {
        const float* tg = T2g + (size_t)(pi_s * 32 + jt * 8 + jj_s) * 128 + pc;
        float4 q0 = *(const float4*)(tg);
        float4 q1 = *(const float4*)(tg + 4);
        __syncthreads();   // prev tile's reads done (jt==0: nothing/A' pending)
        float* td = T2s + pi_s * 1056 + jj_s * 132 + pc;
        *(float4*)(td)     = q0;
        *(float4*)(td + 4) = q1;
        __syncthreads();   // T2s (and on jt==0, As) ready

        #pragma unroll
        for (int pi = 0; pi < 2; ++pi) {
            #pragma unroll
            for (int jj = 0; jj < 8; ++jj) {
                const float* trow = T2s + pi * 1056 + jj * 132 + pr * 8;
                float4 ta = *(const float4*)(trow);
                float4 tb = *(const float4*)(trow + 4);
                const float* arow = As + ((pi * 32) + jt * 8 + jj) * 64 + o4;
                float4 av = *(const float4*)(arow);
                float t8[8] = {ta.x, ta.y, ta.z, ta.w, tb.x, tb.y, tb.z, tb.w};
                #pragma unroll
                for (int pp = 0; pp < 8; ++pp) {
                    acc[pi][pp][0] += t8[pp] * av.x;
                    acc[pi][pp][1] += t8[pp] * av.y;
                    acc[pi][pp][2] += t8[pp] * av.z;
                    acc[pi][pp][3] += t8[pp] * av.w;
                }
            }
        }
    }

    float* op = out + (size_t)(b * 256 + x) * (256 * 64);
    #pragma unroll
    for (int pp = 0; pp < 8; ++pp) {
        int p = pr * 8 + pp;
        float4 lo = make_float4(acc[0][pp][0] + acc[1][pp][0],
                                acc[0][pp][1] + acc[1][pp][1],
                                acc[0][pp][2] + acc[1][pp][2],
                                acc[0][pp][3] + acc[1][pp][3]);
        float4 hi = make_float4(acc[0][pp][0] - acc[1][pp][0],
                                acc[0][pp][1] - acc[1][pp][1],
                                acc[0][pp][2] - acc[1][pp][2],
                                acc[0][pp][3] - acc[1][pp][3]);
        *(float4*)(op + (size_t)p * 64 + o4)         = lo;
        *(float4*)(op + (size_t)(p + 128) * 64 + o4) = hi;
    }
}

// ---------------------------------------------------------------------------
extern "C" void kernel_launch(void* const* d_in, const int* in_sizes, int n_in,
                              void* d_out, int out_size, void* d_ws, size_t ws_size,
                              hipStream_t stream) {
    const float* u   = (const float*)d_in[0];
    const float* wpr = (const float*)d_in[1];
    const float* wpi = (const float*)d_in[2];
    const float* wnr = (const float*)d_in[3];
    const float* wni = (const float*)d_in[4];
    float* out = (float*)d_out;

    char* ws = (char*)d_ws;
    // U : 64*32*8*64  float2 =  8 MiB  @ 0
    // OF:  8*32*64*64 float2 =  8 MiB  @ 8 MiB
    // V : 8*256*32*64 float2 = 32 MiB  @ 16 MiB (A aliases V)
    // Tf: 128 KiB @ 48 MiB; Ti: 128 KiB; Ty: 32 KiB; T2: 32 KiB
    float2* U  = (float2*)(ws);
    float2* OF = (float2*)(ws + 8388608);
    float2* V  = (float2*)(ws + 16777216);
    float2* A  = V;
    float2* Tf = (float2*)(ws + 50331648);
    float2* Ti = (float2*)(ws + 50331648 + 131072);
    float*  Ty = (float*)(ws + 50331648 + 262144);
    float*  T2 = (float*)(ws + 50331648 + 262144 + 32768);

    k_tw<<<128, 256, 0, stream>>>(Tf, Ti, Ty, T2);
    k_fwd_y<<<BB * HH, 256, 0, stream>>>(u, Ty, V);
    k_fwd_x<<<1024, 256, 0, stream>>>(Tf, V, U);
    k_modew<<<1024, 256, 0, stream>>>(wpr, wpi, wnr, wni, U, OF);
    k_inv_x<<<1024, 256, 0, stream>>>(Ti, OF, A);
    k_inv_y<<<BB * HH, 256, 0, stream>>>(T2, A, out);
}

// Round 6
// 224.273 us; speedup vs baseline: 2.1848x; 1.0102x over previous
//
#include <hip/hip_runtime.h>
#include <math.h>

// Sizes fixed by the problem.
#define BB 8
#define HH 256
#define WW 256
#define CC 64
// modes: kx in {0..31} u {224..255} (64 total), ky in {0..31}

__device__ inline void cmac(float2& a, float tx, float ty, float2 v) {
    a.x += tx * v.x - ty * v.y;
    a.y += tx * v.y + ty * v.x;
}

// ---------------------------------------------------------------------------
// K0: all twiddle tables (one kernel, 128 blocks x 256).
// Tf[x][j]  = e^{-2pi i kxa(j) x/256}                       (fwd x-DFT)
// Ti[j][x]  = (2/65536) e^{+2pi i kxa(j) x/256}             (inv x-DFT)
// Ty[y'][par*32+cs*16+m]: cs=0 -> cos(2pi ky y'/256), cs=1 -> -sin(...),
//                         ky = 2m+par                        (fwd y-DFT)
// T2[(pi*32+j)*128+p]: j=2m+ri; ri=0 -> cos(2pi ky p/256), ri=1 -> -sin(...),
//                         ky = 2m+pi                         (inv y-DFT)
// kxa(j) = j (j<32) else j+192.  parity(kxa(j)) == parity(j).
// ---------------------------------------------------------------------------
__global__ __launch_bounds__(256) void k_tw(float2* __restrict__ Tf,
                                            float2* __restrict__ Ti,
                                            float* __restrict__ Ty,
                                            float* __restrict__ T2) {
    int e = blockIdx.x * 256 + threadIdx.x;   // 0..32767
    if (e < 16384) {
        int x = e >> 6;
        int j = e & 63;
        int kxa = j + ((j >> 5) * 192);
        int tt = (kxa * x) & 255;
        float ang = (float)tt * (6.283185307179586f / 256.0f);
        float s, c;
        sincosf(ang, &s, &c);
        Tf[(size_t)x * 64 + j] = make_float2(c, -s);
        const float k = 2.0f / 65536.0f;
        Ti[(size_t)j * 256 + x] = make_float2(c * k, s * k);
    } else {
        int f = e - 16384;
        if (f < 8192) {
            int yp = f >> 6;
            int col = f & 63;
            int par = (col >> 5) & 1;
            int cs = (col >> 4) & 1;
            int m = col & 15;
            int ky = 2 * m + par;
            int tt = (ky * yp) & 255;
            float ang = (float)tt * (6.283185307179586f / 256.0f);
            float s, c;
            sincosf(ang, &s, &c);
            Ty[f] = cs ? -s : c;
        } else {
            int g = f - 8192;
            int pi = g >> 12;
            int j = (g >> 7) & 31;
            int p = g & 127;
            int m = j >> 1, ri = j & 1;
            int ky = 2 * m + pi;
            int tt = (ky * p) & 255;
            float ang = (float)tt * (6.283185307179586f / 256.0f);
            float s, c;
            sincosf(ang, &s, &c);
            T2[g] = ri ? -s : c;
        }
    }
}

// ---------------------------------------------------------------------------
// K1 (GEMM form): V[b][x][ky][i] = sum_{y'<128} Ty[y'][ky-col] *
//                 (u[y'] + (-1)^ky u[y'+128])[i]
// grid = B*H (one (b,x) row), 256 threads.
// launch_bounds (256,4): 128-VGPR cap -> no spills (LDS allows 6 blocks/CU,
// VGPR wants ~90; occupancy ~4-5 blocks/CU).
// ---------------------------------------------------------------------------
__global__ __launch_bounds__(256, 4) void k_fwd_y(const float* __restrict__ u,
                                                  const float* __restrict__ Ty,
                                                  float2* __restrict__ V) {
    __shared__ float ue[32 * 68];
    __shared__ float uo[32 * 68];
    __shared__ float Tt[32 * 68];

    int t = threadIdx.x;
    int b = blockIdx.x >> 8;
    int x = blockIdx.x & 255;
    int i4 = (t & 15) * 4;
    int w = t >> 4;
    int p = w & 1;
    int kyq = w >> 1;
    int yy = t >> 3;
    int c0 = (t & 7) * 8;

    const float* ub = u + ((size_t)(b * HH + x)) * (WW * CC);
    const float* uplane = p ? uo : ue;

    float ar0x=0,ar0y=0,ar0z=0,ar0w=0, ai0x=0,ai0y=0,ai0z=0,ai0w=0;
    float ar1x=0,ar1y=0,ar1z=0,ar1w=0, ai1x=0,ai1y=0,ai1z=0,ai1w=0;

    for (int yt = 0; yt < 4; ++yt) {
        const float* plo = ub + (size_t)(yt * 32 + yy) * CC + c0;
        const float* phi = plo + 128 * CC;
        float4 l0 = *(const float4*)(plo);
        float4 l1 = *(const float4*)(plo + 4);
        float4 h0 = *(const float4*)(phi);
        float4 h1 = *(const float4*)(phi + 4);
        const float* tsrc = Ty + (size_t)(yt * 32 + yy) * 64 + c0;
        float4 t0 = *(const float4*)(tsrc);
        float4 t1 = *(const float4*)(tsrc + 4);

        __syncthreads();   // previous tile's LDS reads complete
        int wb = yy * 68 + c0;
        *(float4*)(ue + wb)     = make_float4(l0.x + h0.x, l0.y + h0.y, l0.z + h0.z, l0.w + h0.w);
        *(float4*)(ue + wb + 4) = make_float4(l1.x + h1.x, l1.y + h1.y, l1.z + h1.z, l1.w + h1.w);
        *(float4*)(uo + wb)     = make_float4(l0.x - h0.x, l0.y - h0.y, l0.z - h0.z, l0.w - h0.w);
        *(float4*)(uo + wb + 4) = make_float4(l1.x - h1.x, l1.y - h1.y, l1.z - h1.z, l1.w - h1.w);
        *(float4*)(Tt + wb)     = t0;
        *(float4*)(Tt + wb + 4) = t1;
        __syncthreads();

        #pragma unroll
        for (int y2 = 0; y2 < 32; ++y2) {
            const float* tb = Tt + y2 * 68 + p * 32 + kyq * 2;
            float2 cp = *(const float2*)(tb);        // cos for m = 2kyq, 2kyq+1
            float2 sp = *(const float2*)(tb + 16);   // -sin for same
            float4 uq = *(const float4*)(uplane + y2 * 68 + i4);
            ar0x += cp.x * uq.x; ar0y += cp.x * uq.y; ar0z += cp.x * uq.z; ar0w += cp.x * uq.w;
            ai0x += sp.x * uq.x; ai0y += sp.x * uq.y; ai0z += sp.x * uq.z; ai0w += sp.x * uq.w;
            ar1x += cp.y * uq.x; ar1y += cp.y * uq.y; ar1z += cp.y * uq.z; ar1w += cp.y * uq.w;
            ai1x += sp.y * uq.x; ai1y += sp.y * uq.y; ai1z += sp.y * uq.z; ai1w += sp.y * uq.w;
        }
    }

    // ky = 2*m + p, m = 2kyq + d  ->  ky = 4kyq + 2d + p
    {
        int ky = 4 * kyq + p;
        float2* vp = V + (size_t)(b * HH + x) * 2048 + ky * 64 + i4;
        *(float4*)(vp)     = make_float4(ar0x, ai0x, ar0y, ai0y);
        *(float4*)(vp + 2) = make_float4(ar0z, ai0z, ar0w, ai0w);
    }
    {
        int ky = 4 * kyq + 2 + p;
        float2* vp = V + (size_t)(b * HH + x) * 2048 + ky * 64 + i4;
        *(float4*)(vp)     = make_float4(ar1x, ai1x, ar1y, ai1y);
        *(float4*)(vp + 2) = make_float4(ar1z, ai1z, ar1w, ai1w);
    }
}

// ---------------------------------------------------------------------------
// K2 (radix-2 GEMM): U[j][ky][b][i] = sum_{x<128} Tf[x][j] *
//                    (V[b][x][ky][i] + (-1)^j V[b][x+128][ky][i])
// grid = 1024: bx = jq + 4*(ky + 32*b). 256 threads.
// ---------------------------------------------------------------------------
__global__ __launch_bounds__(256) void k_fwd_x(const float2* __restrict__ Tf,
                                               const float2* __restrict__ V,
                                               float2* __restrict__ U) {
    __shared__ float sRe[2 * 2048];   // [par][xx*64+i] 16 KB
    __shared__ float sIm[2 * 2048];   // 16 KB
    __shared__ float2 Ts[32 * 16];    // [xx][jj] 4 KB

    int bx = blockIdx.x;
    int jq = bx & 3;
    int ky = (bx >> 2) & 31;
    int b  = bx >> 7;
    int t = threadIdx.x;
    int jr = t >> 5;      // 0..7
    int ir = t & 31;      // 0..31

    float2 a00 = {0,0}, a01 = {0,0}, a10 = {0,0}, a11 = {0,0};

    const float2* vb = V + (size_t)b * (HH * 2048) + ky * 64;
    int vrow = t >> 3;          // 0..31
    int vcol = (t & 7) * 8;     // complex index
    int tjj = (t & 7) * 2;      // 0..14
    int parOff = (jr & 1) * 2048;

    for (int x0 = 0; x0 < 128; x0 += 32) {
        const float2* plo = vb + (size_t)(x0 + vrow) * 2048 + vcol;
        const float2* phi = plo + 128 * 2048;
        float4 l0 = *(const float4*)(plo);
        float4 l1 = *(const float4*)(plo + 2);
        float4 l2 = *(const float4*)(plo + 4);
        float4 l3 = *(const float4*)(plo + 6);
        float4 h0 = *(const float4*)(phi);
        float4 h1 = *(const float4*)(phi + 2);
        float4 h2 = *(const float4*)(phi + 4);
        float4 h3 = *(const float4*)(phi + 6);
        float4 tv = *(const float4*)(Tf + (size_t)(x0 + vrow) * 64 + jq * 16 + tjj);

        __syncthreads();   // previous tile's LDS reads complete
        *(float4*)&Ts[vrow * 16 + tjj] = tv;
        int wb = vrow * 64 + vcol;
        *(float4*)(sRe + wb)            = make_float4(l0.x+h0.x, l0.z+h0.z, l1.x+h1.x, l1.z+h1.z);
        *(float4*)(sRe + wb + 4)        = make_float4(l2.x+h2.x, l2.z+h2.z, l3.x+h3.x, l3.z+h3.z);
        *(float4*)(sIm + wb)            = make_float4(l0.y+h0.y, l0.w+h0.w, l1.y+h1.y, l1.w+h1.w);
        *(float4*)(sIm + wb + 4)        = make_float4(l2.y+h2.y, l2.w+h2.w, l3.y+h3.y, l3.w+h3.w);
        *(float4*)(sRe + 2048 + wb)     = make_float4(l0.x-h0.x, l0.z-h0.z, l1.x-h1.x, l1.z-h1.z);
        *(float4*)(sRe + 2048 + wb + 4) = make_float4(l2.x-h2.x, l2.z-h2.z, l3.x-h3.x, l3.z-h3.z);
        *(float4*)(sIm + 2048 + wb)     = make_float4(l0.y-h0.y, l0.w-h0.w, l1.y-h1.y, l1.w-h1.w);
        *(float4*)(sIm + 2048 + wb + 4) = make_float4(l2.y-h2.y, l2.w-h2.w, l3.y-h3.y, l3.w-h3.w);
        __syncthreads();

        #pragma unroll
        for (int xx = 0; xx < 32; ++xx) {
            float2 t0 = Ts[xx * 16 + jr];
            float2 t1 = Ts[xx * 16 + jr + 8];
            const float* re = sRe + parOff + xx * 64;
            const float* im = sIm + parOff + xx * 64;
            float vr0 = re[ir], vr1 = re[ir + 32];
            float vi0 = im[ir], vi1 = im[ir + 32];
            a00.x += t0.x*vr0 - t0.y*vi0;  a00.y += t0.x*vi0 + t0.y*vr0;
            a01.x += t0.x*vr1 - t0.y*vi1;  a01.y += t0.x*vi1 + t0.y*vr1;
            a10.x += t1.x*vr0 - t1.y*vi0;  a10.y += t1.x*vi0 + t1.y*vr0;
            a11.x += t1.x*vr1 - t1.y*vi1;  a11.y += t1.x*vi1 + t1.y*vr1;
        }
    }

    int j0 = jq * 16 + jr;
    float2* u0 = U + ((size_t)(j0 * 32 + ky) * 8 + b) * 64 + ir;
    u0[0]  = a00;
    u0[32] = a01;
    float2* u1 = U + ((size_t)((j0 + 8) * 32 + ky) * 8 + b) * 64 + ir;
    u1[0]  = a10;
    u1[32] = a11;
}

// ---------------------------------------------------------------------------
// K3 (fused weight-transpose + mode mul):
// OF[b][ky][j][o] = sum_i U[j][ky][b][i] * (wr[i,o,kxl,ky], wi[i,o,kxl,ky])
// grid = 1024: bx = j + 64*kyt + 512*oh  (kyt 0..7 -> 4 ky; oh 0..1 -> 32 o).
// ---------------------------------------------------------------------------
__global__ __launch_bounds__(256) void k_modew(const float* __restrict__ wpr,
                                               const float* __restrict__ wpi,
                                               const float* __restrict__ wnr,
                                               const float* __restrict__ wni,
                                               const float2* __restrict__ U,
                                               float2* __restrict__ OF) {
    __shared__ float2 uS[4 * 8 * 64];   // [kyr][b][i]    16 KB
    __shared__ float2 wS[4 * 8 * 32];   // [kyr][ir][o32]  8 KB (per i-tile)

    int bx = blockIdx.x;
    int j   = bx & 63;
    int kyt = (bx >> 6) & 7;
    int oh  = bx >> 9;
    int ky0 = kyt * 4;
    int sel = j >> 5, kxl = j & 31;
    const float* sr = sel ? wnr : wpr;
    const float* si = sel ? wni : wpi;
    int tid = threadIdx.x;

    const float2* up = U + (size_t)(j * 32 + ky0) * 512;
    #pragma unroll
    for (int k = 0; k < 8; ++k) uS[tid + 256 * k] = up[tid + 256 * k];

    int o32 = tid & 31;
    int bh  = tid >> 5;
    int irS = tid >> 5;
    int ooS = tid & 31;

    float2 acc[4];
    #pragma unroll
    for (int k = 0; k < 4; ++k) acc[k] = make_float2(0.f, 0.f);

    for (int it = 0; it < 8; ++it) {
        __syncthreads();  // uS ready (it==0) / wS reads of prev tile done
        {
            int ig = it * 8 + irS;
            int og = oh * 32 + ooS;
            size_t base = (((size_t)(ig * 64 + og)) * 32 + kxl) * 32 + ky0;
            float4 r0 = *(const float4*)(sr + base);
            float4 q0 = *(const float4*)(si + base);
            float2* wrow = wS + irS * 32 + ooS;
            wrow[0 * 256] = make_float2(r0.x, q0.x);
            wrow[1 * 256] = make_float2(r0.y, q0.y);
            wrow[2 * 256] = make_float2(r0.z, q0.z);
            wrow[3 * 256] = make_float2(r0.w, q0.w);
        }
        __syncthreads();
        #pragma unroll
        for (int ir = 0; ir < 8; ++ir) {
            int ig = it * 8 + ir;
            #pragma unroll
            for (int ky = 0; ky < 4; ++ky) {
                float2 wv = wS[ky * 256 + ir * 32 + o32];
                float2 uv = uS[ky * 512 + bh * 64 + ig];
                acc[ky].x += uv.x * wv.x - uv.y * wv.y;
                acc[ky].y += uv.x * wv.y + uv.y * wv.x;
            }
        }
    }

    int og = oh * 32 + o32;
    #pragma unroll
    for (int ky = 0; ky < 4; ++ky) {
        OF[((size_t)(bh * 32 + ky0 + ky) * 64 + j) * 64 + og] = acc[ky];
    }
}

// ---------------------------------------------------------------------------
// K4 (radix-2 GEMM): for x<128:
//   Se = sum_{even j} Ti[j][x] OF[b][ky][j][o], So = sum_{odd j} ...
//   A[b][x]     = (Se+So)*sc,  A[b][x+128] = (Se-So)*sc   (sc: ky==0 -> 0.5)
// grid = 1024: bx = xt + 4*(ky + 32*b). 256 threads.
// ---------------------------------------------------------------------------
__global__ __launch_bounds__(256) void k_inv_x(const float2* __restrict__ Ti,
                                               const float2* __restrict__ OF,
                                               float2* __restrict__ A) {
    __shared__ float2 Ts[32 * 32];   // [jj][xp]  8 KB
    __shared__ float2 Os[32 * 64];   // [jj][o]  16 KB

    int bx = blockIdx.x;
    int xt = bx & 3;
    int ky = (bx >> 2) & 31;
    int b  = bx >> 7;
    int t = threadIdx.x;
    int or_ = t & 15;
    int xr = t >> 4;     // 0..15

    float2 acc[2][2][4];   // [parity][p][q]
    #pragma unroll
    for (int pa = 0; pa < 2; ++pa)
        #pragma unroll
        for (int p = 0; p < 2; ++p)
            #pragma unroll
            for (int q = 0; q < 4; ++q) acc[pa][p][q] = make_float2(0.f, 0.f);

    const float2* ofb = OF + (size_t)(b * 32 + ky) * 4096;
    int sj = t >> 3;         // 0..31
    int sx = (t & 7) * 4;    // Ts cols (4 complex)
    int so = (t & 7) * 8;    // Os cols (8 complex)

    for (int kh = 0; kh < 2; ++kh) {
        const float2* tsrc = Ti + (size_t)(kh * 32 + sj) * 256 + xt * 32 + sx;
        float4 t0 = *(const float4*)(tsrc);
        float4 t1 = *(const float4*)(tsrc + 2);
        const float2* osrc = ofb + (size_t)(kh * 32 + sj) * 64 + so;
        float4 o0 = *(const float4*)(osrc);
        float4 o1 = *(const float4*)(osrc + 2);
        float4 o2 = *(const float4*)(osrc + 4);
        float4 o3 = *(const float4*)(osrc + 6);

        __syncthreads();
        *(float4*)&Ts[sj * 32 + sx]     = t0;
        *(float4*)&Ts[sj * 32 + sx + 2] = t1;
        float2* od = &Os[sj * 64 + so];
        *(float4*)(od)     = o0;
        *(float4*)(od + 2) = o1;
        *(float4*)(od + 4) = o2;
        *(float4*)(od + 6) = o3;
        __syncthreads();

        #pragma unroll
        for (int jj = 0; jj < 32; ++jj) {
            float4 tp = *(const float4*)&Ts[jj * 32 + xr * 2];
            float2 q0 = Os[jj * 64 + or_];
            float2 q1 = Os[jj * 64 + or_ + 16];
            float2 q2 = Os[jj * 64 + or_ + 32];
            float2 q3 = Os[jj * 64 + or_ + 48];
            const int pa = jj & 1;     // constant after unroll
            cmac(acc[pa][0][0], tp.x, tp.y, q0);
            cmac(acc[pa][0][1], tp.x, tp.y, q1);
            cmac(acc[pa][0][2], tp.x, tp.y, q2);
            cmac(acc[pa][0][3], tp.x, tp.y, q3);
            cmac(acc[pa][1][0], tp.z, tp.w, q0);
            cmac(acc[pa][1][1], tp.z, tp.w, q1);
            cmac(acc[pa][1][2], tp.z, tp.w, q2);
            cmac(acc[pa][1][3], tp.z, tp.w, q3);
        }
    }

    float sc = (ky == 0) ? 0.5f : 1.0f;
    #pragma unroll
    for (int p = 0; p < 2; ++p) {
        int x = xt * 32 + xr * 2 + p;
        float2* alo = A + ((size_t)(b * 256 + x) * 32 + ky) * 64 + or_;
        float2* ahi = A + ((size_t)(b * 256 + x + 128) * 32 + ky) * 64 + or_;
        #pragma unroll
        for (int q = 0; q < 4; ++q) {
            float2 se = acc[0][p][q], so2 = acc[1][p][q];
            alo[16 * q] = make_float2((se.x + so2.x) * sc, (se.y + so2.y) * sc);
            ahi[16 * q] = make_float2((se.x - so2.x) * sc, (se.y - so2.y) * sc);
        }
    }
}

// ---------------------------------------------------------------------------
// K5 (GEMM form): per (b,x):
//   S_pi[p][o] = sum_j T2[pi][j][p] * A'[pi][j][o]   (j = 16m x {re,im}, K=32)
//   out[p][o] = S_0+S_1 ; out[p+128][o] = S_0-S_1    (p in [0,128))
// grid = B*H blocks, 512 threads: og = t&15 (4 o), pr = t>>4 (4 p: pr*4..+3).
// acc[2][4][4] = 32 floats (no spill; VGPR ~70 under the 128 cap).
// A' staged planar (pitch 68); full T2 staged (pitch 132). LDS 50 KB ->
// 3 blocks/CU = 24 waves/CU.
// ---------------------------------------------------------------------------
__global__ __launch_bounds__(512, 2) void k_inv_y(const float* __restrict__ T2g,
                                                  const float2* __restrict__ A,
                                                  float* __restrict__ out) {
    __shared__ float As[2 * 32 * 68];     // [pi][j][o]+pad   17.4 KB
    __shared__ float T2s[2 * 32 * 132];   // [pi][j][p]+pad   33.8 KB

    int t = threadIdx.x;
    int b = blockIdx.x >> 8;
    int x = blockIdx.x & 255;
    int o4 = (t & 15) * 4;
    int pr = t >> 4;            // 0..31 -> p = pr*4 + pp

    float acc[2][4][4];
    #pragma unroll
    for (int pi = 0; pi < 2; ++pi)
        #pragma unroll
        for (int pp = 0; pp < 4; ++pp)
            #pragma unroll
            for (int k = 0; k < 4; ++k) acc[pi][pp][k] = 0.f;

    // stage A' planar: A[b][x][ky][o] -> As[ky&1][2*(ky>>1)+{re,im}][o]
    {
        int ky = t >> 4;            // 0..31
        int oc = (t & 15) * 4;      // complex col
        const float2* ap = A + (size_t)(b * 256 + x) * 2048 + ky * 64 + oc;
        float4 g0 = *(const float4*)(ap);
        float4 g1 = *(const float4*)(ap + 2);
        int pi = ky & 1, m = ky >> 1;
        float* re = As + ((pi * 32) + 2 * m) * 68 + oc;
        float* im = As + ((pi * 32) + 2 * m + 1) * 68 + oc;
        *(float4*)(re) = make_float4(g0.x, g0.z, g1.x, g1.z);
        *(float4*)(im) = make_float4(g0.y, g0.w, g1.y, g1.w);
    }
    // stage full T2: 8192 floats / 512 threads = 16 floats = 4 float4
    {
        int row = t >> 3;           // 0..63 = pi*32 + j
        int c = (t & 7) * 16;       // 0..112
        const float* tg = T2g + (size_t)row * 128 + c;
        float4 q0 = *(const float4*)(tg);
        float4 q1 = *(const float4*)(tg + 4);
        float4 q2 = *(const float4*)(tg + 8);
        float4 q3 = *(const float4*)(tg + 12);
        float* td = T2s + row * 132 + c;
        *(float4*)(td)      = q0;
        *(float4*)(td + 4)  = q1;
        *(float4*)(td + 8)  = q2;
        *(float4*)(td + 12) = q3;
    }
    __syncthreads();

    #pragma unroll
    for (int pi = 0; pi < 2; ++pi) {
        #pragma unroll
        for (int jj = 0; jj < 32; ++jj) {
            float4 ta = *(const float4*)(T2s + (pi * 32 + jj) * 132 + pr * 4);
            float4 av = *(const float4*)(As + (pi * 32 + jj) * 68 + o4);
            acc[pi][0][0] += ta.x * av.x;  acc[pi][0][1] += ta.x * av.y;
            acc[pi][0][2] += ta.x * av.z;  acc[pi][0][3] += ta.x * av.w;
            acc[pi][1][0] += ta.y * av.x;  acc[pi][1][1] += ta.y * av.y;
            acc[pi][1][2] += ta.y * av.z;  acc[pi][1][3] += ta.y * av.w;
            acc[pi][2][0] += ta.z * av.x;  acc[pi][2][1] += ta.z * av.y;
            acc[pi][2][2] += ta.z * av.z;  acc[pi][2][3] += ta.z * av.w;
            acc[pi][3][0] += ta.w * av.x;  acc[pi][3][1] += ta.w * av.y;
            acc[pi][3][2] += ta.w * av.z;  acc[pi][3][3] += ta.w * av.w;
        }
    }

    float* op = out + (size_t)(b * 256 + x) * (256 * 64);
    #pragma unroll
    for (int pp = 0; pp < 4; ++pp) {
        int p = pr * 4 + pp;
        float4 lo = make_float4(acc[0][pp][0] + acc[1][pp][0],
                                acc[0][pp][1] + acc[1][pp][1],
                                acc[0][pp][2] + acc[1][pp][2],
                                acc[0][pp][3] + acc[1][pp][3]);
        float4 hi = make_float4(acc[0][pp][0] - acc[1][pp][0],
                                acc[0][pp][1] - acc[1][pp][1],
                                acc[0][pp][2] - acc[1][pp][2],
                                acc[0][pp][3] - acc[1][pp][3]);
        *(float4*)(op + (size_t)p * 64 + o4)         = lo;
        *(float4*)(op + (size_t)(p + 128) * 64 + o4) = hi;
    }
}

// ---------------------------------------------------------------------------
extern "C" void kernel_launch(void* const* d_in, const int* in_sizes, int n_in,
                              void* d_out, int out_size, void* d_ws, size_t ws_size,
                              hipStream_t stream) {
    const float* u   = (const float*)d_in[0];
    const float* wpr = (const float*)d_in[1];
    const float* wpi = (const float*)d_in[2];
    const float* wnr = (const float*)d_in[3];
    const float* wni = (const float*)d_in[4];
    float* out = (float*)d_out;

    char* ws = (char*)d_ws;
    // U : 64*32*8*64  float2 =  8 MiB  @ 0
    // OF:  8*32*64*64 float2 =  8 MiB  @ 8 MiB
    // V : 8*256*32*64 float2 = 32 MiB  @ 16 MiB (A aliases V)
    // Tf: 128 KiB @ 48 MiB; Ti: 128 KiB; Ty: 32 KiB; T2: 32 KiB
    float2* U  = (float2*)(ws);
    float2* OF = (float2*)(ws + 8388608);
    float2* V  = (float2*)(ws + 16777216);
    float2* A  = V;
    float2* Tf = (float2*)(ws + 50331648);
    float2* Ti = (float2*)(ws + 50331648 + 131072);
    float*  Ty = (float*)(ws + 50331648 + 262144);
    float*  T2 = (float*)(ws + 50331648 + 262144 + 32768);

    k_tw<<<128, 256, 0, stream>>>(Tf, Ti, Ty, T2);
    k_fwd_y<<<BB * HH, 256, 0, stream>>>(u, Ty, V);
    k_fwd_x<<<1024, 256, 0, stream>>>(Tf, V, U);
    k_modew<<<1024, 256, 0, stream>>>(wpr, wpi, wnr, wni, U, OF);
    k_inv_x<<<1024, 256, 0, stream>>>(Ti, OF, A);
    k_inv_y<<<BB * HH, 512, 0, stream>>>(T2, A, out);
}